// Round 1
// baseline (28495.547 us; speedup 1.0000x reference)
//
#include <hip/hip_runtime.h>
#include <math.h>

// Sizes (fixed by the problem)
//  B=32, N=128, EMB=1024, HID=512, L=2, NCLS=7, IN_DIM=3072, TOK=4096

// ---------------------------------------------------------------------------
// Device-scope grid barrier (sense/generation based). All WGs of the grid
// must be co-resident: grids are <= 256 WGs of 256 threads, small LDS.
// ---------------------------------------------------------------------------
__device__ __forceinline__ void gridbar(int* bar, int nwg) {
    __syncthreads();
    if (threadIdx.x == 0) {
        __threadfence();  // flush this XCD's L2 (agent-scope release)
        int g = __hip_atomic_load(bar + 1, __ATOMIC_RELAXED, __HIP_MEMORY_SCOPE_AGENT);
        int v = __hip_atomic_fetch_add(bar, 1, __ATOMIC_ACQ_REL, __HIP_MEMORY_SCOPE_AGENT);
        if (v == nwg - 1) {
            __hip_atomic_store(bar, 0, __ATOMIC_RELAXED, __HIP_MEMORY_SCOPE_AGENT);
            __hip_atomic_store(bar + 1, g + 1, __ATOMIC_RELEASE, __HIP_MEMORY_SCOPE_AGENT);
        } else {
            while (__hip_atomic_load(bar + 1, __ATOMIC_ACQUIRE, __HIP_MEMORY_SCOPE_AGENT) == g) {
                __builtin_amdgcn_s_sleep(1);
            }
        }
        __threadfence();
    }
    __syncthreads();
}

__global__ void init_bar(int* bar) {
    if (threadIdx.x < 16) bar[threadIdx.x] = 0;
}

__device__ __forceinline__ float sigf(float x) { return 1.f / (1.f + __expf(-x)); }

// 256-thread block reductions (4 waves of 64)
__device__ __forceinline__ float blk_sum(float v, float* red) {
    #pragma unroll
    for (int o = 32; o > 0; o >>= 1) v += __shfl_down(v, o, 64);
    const int lane = threadIdx.x & 63, wid = threadIdx.x >> 6;
    __syncthreads();
    if (lane == 0) red[wid] = v;
    __syncthreads();
    return (red[0] + red[1]) + (red[2] + red[3]);
}
__device__ __forceinline__ float blk_max(float v, float* red) {
    #pragma unroll
    for (int o = 32; o > 0; o >>= 1) v = fmaxf(v, __shfl_down(v, o, 64));
    const int lane = threadIdx.x & 63, wid = threadIdx.x >> 6;
    __syncthreads();
    if (lane == 0) red[wid] = v;
    __syncthreads();
    return fmaxf(fmaxf(red[0], red[1]), fmaxf(red[2], red[3]));
}

// ---------------------------------------------------------------------------
// Generic fp32 GEMM:  C[M,N] = act(A[M,K] @ W[N,K]^T + bias[N])
// 64x64 tile, 256 threads, 4x4 per thread. M,N % 64 == 0, K % 16 == 0.
// ---------------------------------------------------------------------------
__global__ __launch_bounds__(256) void gemm_nt(
    const float* __restrict__ A, const float* __restrict__ W,
    const float* __restrict__ bias, float* __restrict__ C,
    int M, int N, int K, int relu)
{
    __shared__ float As[16][68];
    __shared__ float Ws[16][68];
    const int tid = threadIdx.x;
    const int m0 = blockIdx.x * 64;
    const int n0 = blockIdx.y * 64;
    const int lr = tid >> 2;          // 0..63
    const int lk = (tid & 3) << 2;    // 0,4,8,12
    const int tm = (tid & 15) << 2;
    const int tn = (tid >> 4) << 2;
    float acc[4][4] = {};
    const float* Aptr = A + (size_t)(m0 + lr) * K + lk;
    const float* Wptr = W + (size_t)(n0 + lr) * K + lk;
    for (int k0 = 0; k0 < K; k0 += 16) {
        __syncthreads();
        const float4 av = *(const float4*)(Aptr + k0);
        const float4 wv = *(const float4*)(Wptr + k0);
        As[lk + 0][lr] = av.x; As[lk + 1][lr] = av.y;
        As[lk + 2][lr] = av.z; As[lk + 3][lr] = av.w;
        Ws[lk + 0][lr] = wv.x; Ws[lk + 1][lr] = wv.y;
        Ws[lk + 2][lr] = wv.z; Ws[lk + 3][lr] = wv.w;
        __syncthreads();
        #pragma unroll
        for (int kk = 0; kk < 16; ++kk) {
            float a[4], b[4];
            #pragma unroll
            for (int u = 0; u < 4; ++u) { a[u] = As[kk][tm + u]; b[u] = Ws[kk][tn + u]; }
            #pragma unroll
            for (int ii = 0; ii < 4; ++ii)
                #pragma unroll
                for (int jj = 0; jj < 4; ++jj)
                    acc[ii][jj] += a[ii] * b[jj];
        }
    }
    #pragma unroll
    for (int ii = 0; ii < 4; ++ii)
        #pragma unroll
        for (int jj = 0; jj < 4; ++jj) {
            float v = acc[ii][jj] + bias[n0 + tn + jj];
            if (relu) v = fmaxf(v, 0.f);
            C[(size_t)(m0 + tm + ii) * N + n0 + tn + jj] = v;
        }
}

// ---------------------------------------------------------------------------
// mlp0: x1 = relu(concat([H0,H1,H2,feat,lstm_out], -1) @ W[512,3072]^T + b)
// A gathered from 5 sources; K-tiles (16) never cross part boundaries.
// ---------------------------------------------------------------------------
__global__ __launch_bounds__(256) void gemm_cat(
    const float* __restrict__ H0, const float* __restrict__ H1,
    const float* __restrict__ H2, const float* __restrict__ feat,
    const float* __restrict__ lstm, const float* __restrict__ W,
    const float* __restrict__ bias, float* __restrict__ C)
{
    __shared__ float As[16][68];
    __shared__ float Ws[16][68];
    const int tid = threadIdx.x;
    const int m0 = blockIdx.x * 64;
    const int n0 = blockIdx.y * 64;
    const int lr = tid >> 2;
    const int lk = (tid & 3) << 2;
    const int tm = (tid & 15) << 2;
    const int tn = (tid >> 4) << 2;
    float acc[4][4] = {};
    for (int k0 = 0; k0 < 3072; k0 += 16) {
        const float* src; int kloc, Kp;
        if (k0 < 512)       { src = H0;   kloc = k0;        Kp = 512;  }
        else if (k0 < 1024) { src = H1;   kloc = k0 - 512;  Kp = 512;  }
        else if (k0 < 1536) { src = H2;   kloc = k0 - 1024; Kp = 512;  }
        else if (k0 < 2560) { src = feat; kloc = k0 - 1536; Kp = 1024; }
        else                { src = lstm; kloc = k0 - 2560; Kp = 512;  }
        __syncthreads();
        const float4 av = *(const float4*)(src + (size_t)(m0 + lr) * Kp + kloc + lk);
        const float4 wv = *(const float4*)(W + (size_t)(n0 + lr) * 3072 + k0 + lk);
        As[lk + 0][lr] = av.x; As[lk + 1][lr] = av.y;
        As[lk + 2][lr] = av.z; As[lk + 3][lr] = av.w;
        Ws[lk + 0][lr] = wv.x; Ws[lk + 1][lr] = wv.y;
        Ws[lk + 2][lr] = wv.z; Ws[lk + 3][lr] = wv.w;
        __syncthreads();
        #pragma unroll
        for (int kk = 0; kk < 16; ++kk) {
            float a[4], b[4];
            #pragma unroll
            for (int u = 0; u < 4; ++u) { a[u] = As[kk][tm + u]; b[u] = Ws[kk][tn + u]; }
            #pragma unroll
            for (int ii = 0; ii < 4; ++ii)
                #pragma unroll
                for (int jj = 0; jj < 4; ++jj)
                    acc[ii][jj] += a[ii] * b[jj];
        }
    }
    #pragma unroll
    for (int ii = 0; ii < 4; ++ii)
        #pragma unroll
        for (int jj = 0; jj < 4; ++jj) {
            float v = fmaxf(acc[ii][jj] + bias[n0 + tn + jj], 0.f);
            C[(size_t)(m0 + tm + ii) * 512 + n0 + tn + jj] = v;
        }
}

// ---------------------------------------------------------------------------
// Persistent LSTM: 32 steps over time axis (=B of features), batch=128.
// 256 WGs: rb = row-block of 16 rows, cb = 16 hidden cols (x4 gates).
// h double-buffered in global (one gridbar per step); c lives in registers.
// ---------------------------------------------------------------------------
__global__ __launch_bounds__(256) void lstm_pers(
    const float* __restrict__ gi,   // 32 x 128 x 2048  (x@Wih^T + bih)
    const float* __restrict__ Whh,  // 2048 x 512
    const float* __restrict__ bhh,  // 2048
    float* __restrict__ hbuf,       // 2 x 128 x 512
    float* __restrict__ ys,         // 32 x 128 x 512
    int* bar)
{
    const int wg = blockIdx.x;      // 256
    const int tid = threadIdx.x;
    const int rb = wg >> 5;         // 0..7
    const int cb = wg & 31;         // 0..31
    const int j = tid >> 4;         // 0..15 local hidden
    const int r = tid & 15;         // 0..15 local row
    const int grow = rb * 16 + r;
    const int ghid = cb * 16 + j;
    __shared__ float hs[16 * 516];
    hbuf[wg * 256 + tid] = 0.f;     // zero parity-0 h (covers 128*512 exactly)
    float c_reg = 0.f;
    const float bi = bhh[ghid], bf = bhh[512 + ghid];
    const float bg = bhh[1024 + ghid], bo = bhh[1536 + ghid];
    const float* Wi = Whh + (size_t)ghid * 512;
    const float* Wf = Whh + (size_t)(512 + ghid) * 512;
    const float* Wg = Whh + (size_t)(1024 + ghid) * 512;
    const float* Wo = Whh + (size_t)(1536 + ghid) * 512;
    gridbar(bar, 256);
    for (int t = 0; t < 32; ++t) {
        const int par = t & 1;
        const float* hsrc = hbuf + par * (128 * 512);
        for (int idx = tid; idx < 16 * 512; idx += 256) {
            const int rr = idx >> 9, kk = idx & 511;
            hs[rr * 516 + kk] = hsrc[(rb * 16 + rr) * 512 + kk];
        }
        __syncthreads();
        float s_i = bi, s_f = bf, s_g = bg, s_o = bo;
        const float* hrow = hs + r * 516;
        for (int k = 0; k < 512; k += 4) {
            const float4 hv  = *(const float4*)(hrow + k);
            const float4 wi4 = *(const float4*)(Wi + k);
            const float4 wf4 = *(const float4*)(Wf + k);
            const float4 wg4 = *(const float4*)(Wg + k);
            const float4 wo4 = *(const float4*)(Wo + k);
            s_i += hv.x*wi4.x + hv.y*wi4.y + hv.z*wi4.z + hv.w*wi4.w;
            s_f += hv.x*wf4.x + hv.y*wf4.y + hv.z*wf4.z + hv.w*wf4.w;
            s_g += hv.x*wg4.x + hv.y*wg4.y + hv.z*wg4.z + hv.w*wg4.w;
            s_o += hv.x*wo4.x + hv.y*wo4.y + hv.z*wo4.z + hv.w*wo4.w;
        }
        const float* gir = gi + ((size_t)t * 128 + grow) * 2048;
        s_i += gir[ghid]; s_f += gir[512 + ghid];
        s_g += gir[1024 + ghid]; s_o += gir[1536 + ghid];
        c_reg = sigf(s_f) * c_reg + sigf(s_i) * tanhf(s_g);
        const float hnew = sigf(s_o) * tanhf(c_reg);
        ys[((size_t)t * 128 + grow) * 512 + ghid] = hnew;
        hbuf[(1 - par) * (128 * 512) + grow * 512 + ghid] = hnew;
        gridbar(bar, 256);
    }
}

// ---------------------------------------------------------------------------
// Persistent GNN layer. 128 WGs (b = wg>>2, cb = wg&3). Per step i:
//   Phase B : GG[32,3072] = M_i @ [cWhh | pWih]^T + [cbhh | pbih]   (col-split)
//   Phase CA: gates -> h_i (redundant per cb); Hout/hk; V0/V1[i] col-slice;
//             softmax(i+1) + M_{i+1} col-slice (n=i term from local LDS V).
// 2 grid barriers per step. M double-buffered by parity.
// ---------------------------------------------------------------------------
__global__ __launch_bounds__(256) void gnn_layer(
    const float* __restrict__ Hin, float* __restrict__ Hout,
    const float* __restrict__ adj, const float* __restrict__ smk,
    const float* __restrict__ preQc, const float* __restrict__ preQp,
    const float* __restrict__ cWhh, const float* __restrict__ pWih,
    const float* __restrict__ cbhh, const float* __restrict__ pbih,
    const float* __restrict__ Wr0, const float* __restrict__ Wr1,
    const float* __restrict__ attnW, const float* __restrict__ attnb,
    float* __restrict__ V0, float* __restrict__ V1,
    float* __restrict__ hk, float* __restrict__ Mbuf,
    float* __restrict__ GG, int* bar)
{
    const int wg = blockIdx.x;   // 128
    const int tid = threadIdx.x; // 256
    __shared__ float sm[1024];
    float* hs  = sm;         // 512
    float* v0s = sm + 512;   // 128
    float* v1s = sm + 640;   // 128
    float* wsf = sm + 768;   // 128
    float* red = sm + 896;   // 4
    const int b  = wg >> 2;
    const int cb = wg & 3;
    if (wg < 32) {           // zero M parity-0
        Mbuf[wg * 512 + tid] = 0.f;
        Mbuf[wg * 512 + 256 + tid] = 0.f;
    }
    gridbar(bar, 128);
    for (int i = 0; i < 128; ++i) {
        const int par = i & 1;
        // ---------------- Phase B ----------------
        {
            const float* Mv = Mbuf + par * (32 * 512);
            const int r  = tid >> 3;                 // 0..31 (batch row)
            const int c0 = wg * 24 + (tid & 7) * 3;  // 3 consecutive cols
            const float* w0 = (c0     < 1536) ? cWhh + (size_t)c0 * 512
                                              : pWih + (size_t)(c0 - 1536) * 512;
            const float* w1 = (c0 + 1 < 1536) ? cWhh + (size_t)(c0 + 1) * 512
                                              : pWih + (size_t)(c0 + 1 - 1536) * 512;
            const float* w2 = (c0 + 2 < 1536) ? cWhh + (size_t)(c0 + 2) * 512
                                              : pWih + (size_t)(c0 + 2 - 1536) * 512;
            float a0 = (c0     < 1536) ? cbhh[c0]       : pbih[c0 - 1536];
            float a1 = (c0 + 1 < 1536) ? cbhh[c0 + 1]   : pbih[c0 + 1 - 1536];
            float a2 = (c0 + 2 < 1536) ? cbhh[c0 + 2]   : pbih[c0 + 2 - 1536];
            const float* mr = Mv + r * 512;
            for (int k = 0; k < 512; k += 4) {
                const float4 m4 = *(const float4*)(mr + k);
                const float4 f0 = *(const float4*)(w0 + k);
                const float4 f1 = *(const float4*)(w1 + k);
                const float4 f2 = *(const float4*)(w2 + k);
                a0 += m4.x*f0.x + m4.y*f0.y + m4.z*f0.z + m4.w*f0.w;
                a1 += m4.x*f1.x + m4.y*f1.y + m4.z*f1.z + m4.w*f1.w;
                a2 += m4.x*f2.x + m4.y*f2.y + m4.z*f2.z + m4.w*f2.w;
            }
            GG[r * 3072 + c0]     = a0;
            GG[r * 3072 + c0 + 1] = a1;
            GG[r * 3072 + c0 + 2] = a2;
        }
        gridbar(bar, 128);
        // ---------------- Phase CA ----------------
        {
            const float* Mv = Mbuf + par * (32 * 512) + b * 512;
            const float* pc = preQc + ((size_t)b * 128 + i) * 1536;
            const float* pp = preQp + ((size_t)b * 128 + i) * 1536;
            const float* gg = GG + b * 3072;
            const float* q  = Hin + ((size_t)b * 128 + i) * 512;
            float hkp = 0.f;
            #pragma unroll
            for (int rep = 0; rep < 2; ++rep) {
                const int jj = tid + rep * 256;
                const float rc = sigf(pc[jj] + gg[jj]);
                const float zc = sigf(pc[512 + jj] + gg[512 + jj]);
                const float nc = tanhf(pc[1024 + jj] + rc * gg[1024 + jj]);
                const float oc = (1.f - zc) * nc + zc * Mv[jj];
                const float rp = sigf(gg[1536 + jj] + pp[jj]);
                const float zp = sigf(gg[2048 + jj] + pp[512 + jj]);
                const float np = tanhf(gg[2560 + jj] + rp * pp[1024 + jj]);
                const float op = (1.f - zp) * np + zp * q[jj];
                const float h = oc + op;
                hs[jj] = h;
                if (cb == 0) Hout[((size_t)b * 128 + i) * 512 + jj] = h;
                hkp += h * attnW[512 + jj];   // wk
            }
            const float hk_i = blk_sum(hkp, red);
            if (cb == 0 && tid == 0) hk[b * 128 + i] = hk_i;
            __syncthreads();
            // V projection for this col-slice
            const int cc = cb * 128 + (tid & 127);
            const int sel = tid >> 7;
            const float* wr = (sel ? Wr1 : Wr0) + (size_t)cc * 512;
            float vacc = 0.f;
            for (int k = 0; k < 512; k += 4) {
                const float4 h4 = *(const float4*)(hs + k);
                const float4 w4 = *(const float4*)(wr + k);
                vacc += h4.x*w4.x + h4.y*w4.y + h4.z*w4.z + h4.w*w4.w;
            }
            (sel ? V1 : V0)[((size_t)b * 128 + i) * 512 + cc] = vacc;
            if (sel) v1s[tid & 127] = vacc; else v0s[tid & 127] = vacc;
            // attention + next M
            if (i < 127) {
                const int nx = i + 1;
                const float* qn = Hin + ((size_t)b * 128 + nx) * 512;
                const float qp2 = qn[tid] * attnW[tid] + qn[tid + 256] * attnW[tid + 256];
                const float qdot = blk_sum(qp2, red) + attnb[0];
                const float* ar = adj + ((size_t)b * 128 + nx) * 128;
                float alpha = -INFINITY;
                if (tid <= i) {
                    const float hkn = (tid == i) ? hk_i : hk[b * 128 + tid];
                    alpha = qdot + hkn - (1.f - ar[tid]) * 1e30f;
                }
                const float mx = blk_max(alpha, red);
                const float e = (tid <= i) ? __expf(alpha - mx) : 0.f;
                const float esum = blk_sum(e, red);
                if (tid < 128) wsf[tid] = e / esum;
                __syncthreads();
                const float* sr = smk + ((size_t)b * 128 + nx) * 128;
                if (tid < 128) {
                    const int d = cb * 128 + tid;
                    float macc = 0.f;
                    for (int n = 0; n < i; ++n) {
                        const float* vsrc = (sr[n] != 0.f) ? V0 : V1;
                        macc += wsf[n] * vsrc[((size_t)b * 128 + n) * 512 + d];
                    }
                    macc += wsf[i] * ((sr[i] != 0.f) ? v0s[tid] : v1s[tid]);
                    Mbuf[(1 - par) * (32 * 512) + b * 512 + d] = macc;
                }
            }
        }
        gridbar(bar, 128);
    }
}

// ---------------------------------------------------------------------------
// out = x2 @ out_W[7,512]^T + out_b   (256 WGs x 16 rows)
// ---------------------------------------------------------------------------
__global__ __launch_bounds__(256) void out_gemm(
    const float* __restrict__ x2, const float* __restrict__ W,
    const float* __restrict__ bias, float* __restrict__ out)
{
    __shared__ float xs[16 * 516];
    const int tid = threadIdx.x;
    const int r0 = blockIdx.x * 16;
    for (int idx = tid; idx < 16 * 512; idx += 256) {
        const int rr = idx >> 9, kk = idx & 511;
        xs[rr * 516 + kk] = x2[(size_t)(r0 + rr) * 512 + kk];
    }
    __syncthreads();
    if (tid < 128) {
        const int r = tid >> 3, c = tid & 7;
        if (c < 7) {
            float acc = bias[c];
            const float* wr = W + c * 512;
            const float* xr = xs + r * 516;
            for (int k = 0; k < 512; ++k) acc += xr[k] * wr[k];
            out[(size_t)(r0 + r) * 7 + c] = acc;
        }
    }
}

// ---------------------------------------------------------------------------
extern "C" void kernel_launch(void* const* d_in, const int* in_sizes, int n_in,
                              void* d_out, int out_size, void* d_ws, size_t ws_size,
                              hipStream_t stream) {
    (void)in_sizes; (void)n_in; (void)out_size; (void)ws_size;
    const float* feat     = (const float*)d_in[0];
    const float* adj      = (const float*)d_in[1];
    const float* smask    = (const float*)d_in[2];
    const float* lstm_Wih = (const float*)d_in[5];
    const float* lstm_Whh = (const float*)d_in[6];
    const float* lstm_bih = (const float*)d_in[7];
    const float* lstm_bhh = (const float*)d_in[8];
    const float* fc1_W    = (const float*)d_in[9];
    const float* fc1_b    = (const float*)d_in[10];
    const float* attn_W   = (const float*)d_in[11];
    const float* attn_b   = (const float*)d_in[12];
    const float* Wr0      = (const float*)d_in[13];
    const float* Wr1      = (const float*)d_in[14];
    const float* gruC_Wih = (const float*)d_in[15];
    const float* gruC_Whh = (const float*)d_in[16];
    const float* gruC_bih = (const float*)d_in[17];
    const float* gruC_bhh = (const float*)d_in[18];
    const float* gruP_Wih = (const float*)d_in[19];
    const float* gruP_Whh = (const float*)d_in[20];
    const float* gruP_bih = (const float*)d_in[21];
    const float* gruP_bhh = (const float*)d_in[22];
    const float* mlp0_W   = (const float*)d_in[23];
    const float* mlp0_b   = (const float*)d_in[24];
    const float* mlp1_W   = (const float*)d_in[25];
    const float* mlp1_b   = (const float*)d_in[26];
    const float* out_W    = (const float*)d_in[27];
    const float* out_b    = (const float*)d_in[28];

    // workspace layout (floats); total ~33.82M floats ~135.3 MB
    float* ws       = (float*)d_ws;
    float* lstm_gi  = ws;                       // 4096*2048
    float* lstm_out = lstm_gi + 8388608;        // 4096*512
    float* H0       = lstm_out + 2097152;
    float* H1       = H0 + 2097152;
    float* H2       = H1 + 2097152;
    float* preQc    = H2 + 2097152;             // 4096*1536
    float* preQp    = preQc + 6291456;
    float* V0       = preQp + 6291456;          // 4096*512 (reused as x1)
    float* V1       = V0 + 2097152;             // (reused as x2)
    float* hkbuf    = V1 + 2097152;             // 32*128
    float* Mbuf     = hkbuf + 4096;             // 2*32*512
    float* GG       = Mbuf + 32768;             // 32*3072
    float* hbuf     = GG + 98304;               // 2*128*512
    int*   bar      = (int*)(hbuf + 131072);    // 16 ints

    const dim3 blk(256);
    init_bar<<<1, 64, 0, stream>>>(bar);

    // H0 = relu(feat @ fc1^T + b)
    gemm_nt<<<dim3(64, 8), blk, 0, stream>>>(feat, fc1_W, fc1_b, H0, 4096, 512, 1024, 1);
    // lstm_gi = feat @ lstm_Wih^T + bih
    gemm_nt<<<dim3(64, 32), blk, 0, stream>>>(feat, lstm_Wih, lstm_bih, lstm_gi, 4096, 2048, 1024, 0);
    // LSTM scan
    lstm_pers<<<256, blk, 0, stream>>>(lstm_gi, lstm_Whh, lstm_bhh, hbuf, lstm_out, bar);

    for (int l = 0; l < 2; ++l) {
        const float* Hin = l ? H1 : H0;
        float* Ho = l ? H2 : H1;
        // preQc = Hin @ cWih^T + cbih ; preQp = Hin @ pWhh^T + pbhh
        gemm_nt<<<dim3(64, 24), blk, 0, stream>>>(Hin, gruC_Wih + (size_t)l * 1536 * 512,
                                                  gruC_bih + l * 1536, preQc, 4096, 1536, 512, 0);
        gemm_nt<<<dim3(64, 24), blk, 0, stream>>>(Hin, gruP_Whh + (size_t)l * 1536 * 512,
                                                  gruP_bhh + l * 1536, preQp, 4096, 1536, 512, 0);
        gnn_layer<<<128, blk, 0, stream>>>(Hin, Ho, adj, smask, preQc, preQp,
                                           gruC_Whh + (size_t)l * 1536 * 512,
                                           gruP_Wih + (size_t)l * 1536 * 512,
                                           gruC_bhh + l * 1536, gruP_bih + l * 1536,
                                           Wr0 + (size_t)l * 512 * 512,
                                           Wr1 + (size_t)l * 512 * 512,
                                           attn_W + l * 1024, attn_b + l,
                                           V0, V1, hkbuf, Mbuf, GG, bar + 4 + l * 4);
    }

    float* x1 = V0;  // V0/V1 dead after GNN layers
    float* x2 = V1;
    gemm_cat<<<dim3(64, 8), blk, 0, stream>>>(H0, H1, H2, feat, lstm_out, mlp0_W, mlp0_b, x1);
    gemm_nt<<<dim3(64, 8), blk, 0, stream>>>(x1, mlp1_W, mlp1_b, x2, 4096, 512, 512, 1);
    out_gemm<<<256, blk, 0, stream>>>(x2, out_W, out_b, (float*)d_out);
}

// Round 2
// 21626.057 us; speedup vs baseline: 1.3176x; 1.3176x over previous
//
#include <hip/hip_runtime.h>
#include <math.h>

// Sizes: B=32, N=128, EMB=1024, HID=512, L=2, NCLS=7, IN_DIM=3072, TOK=4096

#define AGENT __HIP_MEMORY_SCOPE_AGENT

// Coherent (cross-XCD) scalar accesses: relaxed agent-scope atomics lower to
// sc1-flagged global ops that read/write the shared coherence point, WITHOUT
// the bulk L2 writeback/invalidate that __threadfence()/acquire-release emit.
__device__ __forceinline__ float ldc(const float* p) {
    return __hip_atomic_load(p, __ATOMIC_RELAXED, AGENT);
}
__device__ __forceinline__ void stc(float* p, float v) {
    __hip_atomic_store(p, v, __ATOMIC_RELAXED, AGENT);
}

// ---------------------------------------------------------------------------
// Fence-light device-scope grid barrier. Correctness contract: all cross-WG
// data is written with stc() and read with ldc(); __syncthreads() drains each
// wave's vmcnt before s_barrier, so sc1 stores are globally visible before
// the arrive-increment. No cache-flush instructions anywhere.
// ---------------------------------------------------------------------------
__device__ __forceinline__ void gridbar(int* bar, int nwg) {
    __syncthreads();   // drains vmcnt/lgkmcnt for every wave, then s_barrier
    if (threadIdx.x == 0) {
        int g = __hip_atomic_load(bar + 1, __ATOMIC_RELAXED, AGENT);
        int v = __hip_atomic_fetch_add(bar, 1, __ATOMIC_RELAXED, AGENT);
        if (v == nwg - 1) {
            __hip_atomic_store(bar, 0, __ATOMIC_RELAXED, AGENT);
            __builtin_amdgcn_s_waitcnt(0);   // reset visible before gen bump
            __hip_atomic_store(bar + 1, g + 1, __ATOMIC_RELAXED, AGENT);
        } else {
            while (__hip_atomic_load(bar + 1, __ATOMIC_RELAXED, AGENT) == g) {
                __builtin_amdgcn_s_sleep(2);
            }
        }
        __asm__ __volatile__("" ::: "memory");  // no compiler reordering past spin
    }
    __syncthreads();
}

__global__ void init_bar(int* bar) {
    if (threadIdx.x < 16) bar[threadIdx.x] = 0;
}

__device__ __forceinline__ float sigf(float x) { return 1.f / (1.f + __expf(-x)); }

__device__ __forceinline__ float blk_sum(float v, float* red) {
    #pragma unroll
    for (int o = 32; o > 0; o >>= 1) v += __shfl_down(v, o, 64);
    const int lane = threadIdx.x & 63, wid = threadIdx.x >> 6;
    __syncthreads();
    if (lane == 0) red[wid] = v;
    __syncthreads();
    return (red[0] + red[1]) + (red[2] + red[3]);
}
__device__ __forceinline__ float blk_max(float v, float* red) {
    #pragma unroll
    for (int o = 32; o > 0; o >>= 1) v = fmaxf(v, __shfl_down(v, o, 64));
    const int lane = threadIdx.x & 63, wid = threadIdx.x >> 6;
    __syncthreads();
    if (lane == 0) red[wid] = v;
    __syncthreads();
    return fmaxf(fmaxf(red[0], red[1]), fmaxf(red[2], red[3]));
}

// ---------------------------------------------------------------------------
// Generic fp32 GEMM: C = act(A[M,K] @ W[N,K]^T + bias). 64x64 tile.
// ---------------------------------------------------------------------------
__global__ __launch_bounds__(256) void gemm_nt(
    const float* __restrict__ A, const float* __restrict__ W,
    const float* __restrict__ bias, float* __restrict__ C,
    int M, int N, int K, int relu)
{
    __shared__ float As[16][68];
    __shared__ float Ws[16][68];
    const int tid = threadIdx.x;
    const int m0 = blockIdx.x * 64;
    const int n0 = blockIdx.y * 64;
    const int lr = tid >> 2;
    const int lk = (tid & 3) << 2;
    const int tm = (tid & 15) << 2;
    const int tn = (tid >> 4) << 2;
    float acc[4][4] = {};
    const float* Aptr = A + (size_t)(m0 + lr) * K + lk;
    const float* Wptr = W + (size_t)(n0 + lr) * K + lk;
    for (int k0 = 0; k0 < K; k0 += 16) {
        __syncthreads();
        const float4 av = *(const float4*)(Aptr + k0);
        const float4 wv = *(const float4*)(Wptr + k0);
        As[lk + 0][lr] = av.x; As[lk + 1][lr] = av.y;
        As[lk + 2][lr] = av.z; As[lk + 3][lr] = av.w;
        Ws[lk + 0][lr] = wv.x; Ws[lk + 1][lr] = wv.y;
        Ws[lk + 2][lr] = wv.z; Ws[lk + 3][lr] = wv.w;
        __syncthreads();
        #pragma unroll
        for (int kk = 0; kk < 16; ++kk) {
            float a[4], b[4];
            #pragma unroll
            for (int u = 0; u < 4; ++u) { a[u] = As[kk][tm + u]; b[u] = Ws[kk][tn + u]; }
            #pragma unroll
            for (int ii = 0; ii < 4; ++ii)
                #pragma unroll
                for (int jj = 0; jj < 4; ++jj)
                    acc[ii][jj] += a[ii] * b[jj];
        }
    }
    #pragma unroll
    for (int ii = 0; ii < 4; ++ii)
        #pragma unroll
        for (int jj = 0; jj < 4; ++jj) {
            float v = acc[ii][jj] + bias[n0 + tn + jj];
            if (relu) v = fmaxf(v, 0.f);
            C[(size_t)(m0 + tm + ii) * N + n0 + tn + jj] = v;
        }
}

// ---------------------------------------------------------------------------
// mlp0 with fused 5-way concat
// ---------------------------------------------------------------------------
__global__ __launch_bounds__(256) void gemm_cat(
    const float* __restrict__ H0, const float* __restrict__ H1,
    const float* __restrict__ H2, const float* __restrict__ feat,
    const float* __restrict__ lstm, const float* __restrict__ W,
    const float* __restrict__ bias, float* __restrict__ C)
{
    __shared__ float As[16][68];
    __shared__ float Ws[16][68];
    const int tid = threadIdx.x;
    const int m0 = blockIdx.x * 64;
    const int n0 = blockIdx.y * 64;
    const int lr = tid >> 2;
    const int lk = (tid & 3) << 2;
    const int tm = (tid & 15) << 2;
    const int tn = (tid >> 4) << 2;
    float acc[4][4] = {};
    for (int k0 = 0; k0 < 3072; k0 += 16) {
        const float* src; int kloc, Kp;
        if (k0 < 512)       { src = H0;   kloc = k0;        Kp = 512;  }
        else if (k0 < 1024) { src = H1;   kloc = k0 - 512;  Kp = 512;  }
        else if (k0 < 1536) { src = H2;   kloc = k0 - 1024; Kp = 512;  }
        else if (k0 < 2560) { src = feat; kloc = k0 - 1536; Kp = 1024; }
        else                { src = lstm; kloc = k0 - 2560; Kp = 512;  }
        __syncthreads();
        const float4 av = *(const float4*)(src + (size_t)(m0 + lr) * Kp + kloc + lk);
        const float4 wv = *(const float4*)(W + (size_t)(n0 + lr) * 3072 + k0 + lk);
        As[lk + 0][lr] = av.x; As[lk + 1][lr] = av.y;
        As[lk + 2][lr] = av.z; As[lk + 3][lr] = av.w;
        Ws[lk + 0][lr] = wv.x; Ws[lk + 1][lr] = wv.y;
        Ws[lk + 2][lr] = wv.z; Ws[lk + 3][lr] = wv.w;
        __syncthreads();
        #pragma unroll
        for (int kk = 0; kk < 16; ++kk) {
            float a[4], b[4];
            #pragma unroll
            for (int u = 0; u < 4; ++u) { a[u] = As[kk][tm + u]; b[u] = Ws[kk][tn + u]; }
            #pragma unroll
            for (int ii = 0; ii < 4; ++ii)
                #pragma unroll
                for (int jj = 0; jj < 4; ++jj)
                    acc[ii][jj] += a[ii] * b[jj];
        }
    }
    #pragma unroll
    for (int ii = 0; ii < 4; ++ii)
        #pragma unroll
        for (int jj = 0; jj < 4; ++jj) {
            float v = fmaxf(acc[ii][jj] + bias[n0 + tn + jj], 0.f);
            C[(size_t)(m0 + tm + ii) * 512 + n0 + tn + jj] = v;
        }
}

// ---------------------------------------------------------------------------
// Persistent LSTM. 256 WGs (rb=row-block of 16, cb=16 hidden cols x 4 gates).
// h exchanged via sc1 (coherent) accesses; weights stay cached in L2.
// ---------------------------------------------------------------------------
__global__ __launch_bounds__(256) void lstm_pers(
    const float* __restrict__ gi, const float* __restrict__ Whh,
    const float* __restrict__ bhh, float* __restrict__ hbuf,
    float* __restrict__ ys, int* bar)
{
    const int wg = blockIdx.x;
    const int tid = threadIdx.x;
    const int rb = wg >> 5;
    const int cb = wg & 31;
    const int j = tid >> 4;
    const int r = tid & 15;
    const int grow = rb * 16 + r;
    const int ghid = cb * 16 + j;
    __shared__ float hs[16 * 516];
    stc(hbuf + wg * 256 + tid, 0.f);   // zero parity-0 h at coherence point
    float c_reg = 0.f;
    const float bi = bhh[ghid], bf = bhh[512 + ghid];
    const float bg = bhh[1024 + ghid], bo = bhh[1536 + ghid];
    const float* Wi = Whh + (size_t)ghid * 512;
    const float* Wf = Whh + (size_t)(512 + ghid) * 512;
    const float* Wg = Whh + (size_t)(1024 + ghid) * 512;
    const float* Wo = Whh + (size_t)(1536 + ghid) * 512;
    gridbar(bar, 256);
    for (int t = 0; t < 32; ++t) {
        const int par = t & 1;
        const float* hsrc = hbuf + par * (128 * 512) + rb * 16 * 512;
        float tmp[32];
        #pragma unroll
        for (int u = 0; u < 32; ++u) tmp[u] = ldc(hsrc + tid + u * 256);
        #pragma unroll
        for (int u = 0; u < 32; ++u) {
            const int idx = tid + u * 256;
            hs[(idx >> 9) * 516 + (idx & 511)] = tmp[u];
        }
        __syncthreads();
        float s_i = bi, s_f = bf, s_g = bg, s_o = bo;
        const float* hrow = hs + r * 516;
        for (int k = 0; k < 512; k += 4) {
            const float4 hv  = *(const float4*)(hrow + k);
            const float4 wi4 = *(const float4*)(Wi + k);
            const float4 wf4 = *(const float4*)(Wf + k);
            const float4 wg4 = *(const float4*)(Wg + k);
            const float4 wo4 = *(const float4*)(Wo + k);
            s_i += hv.x*wi4.x + hv.y*wi4.y + hv.z*wi4.z + hv.w*wi4.w;
            s_f += hv.x*wf4.x + hv.y*wf4.y + hv.z*wf4.z + hv.w*wf4.w;
            s_g += hv.x*wg4.x + hv.y*wg4.y + hv.z*wg4.z + hv.w*wg4.w;
            s_o += hv.x*wo4.x + hv.y*wo4.y + hv.z*wo4.z + hv.w*wo4.w;
        }
        const float* gir = gi + ((size_t)t * 128 + grow) * 2048;
        s_i += gir[ghid]; s_f += gir[512 + ghid];
        s_g += gir[1024 + ghid]; s_o += gir[1536 + ghid];
        c_reg = sigf(s_f) * c_reg + sigf(s_i) * tanhf(s_g);
        const float hnew = sigf(s_o) * tanhf(c_reg);
        ys[((size_t)t * 128 + grow) * 512 + ghid] = hnew;
        stc(hbuf + (1 - par) * (128 * 512) + grow * 512 + ghid, hnew);
        gridbar(bar, 256);
    }
}

// ---------------------------------------------------------------------------
// Persistent GNN layer, 128 WGs, 2 barriers/step.
// Phase B : WG=(bgrp of 8 batches, cblk of 96 cols): GG = M @ [cWhh|pWih]^T.
//           M slice staged to LDS via sc1 loads; weight rows streamed from a
//           warm L2 (read once per WG, x4 batch-group duplication only).
// Phase CA: gates->h; hk; V slice; softmax(i+1); M_{i+1} (streamed FMA loop,
//           mask select pre-folded into wL0/wL1 weights in LDS).
// ---------------------------------------------------------------------------
__global__ __launch_bounds__(256) void gnn_layer(
    const float* __restrict__ Hin, float* __restrict__ Hout,
    const float* __restrict__ adj, const float* __restrict__ smk,
    const float* __restrict__ preQc, const float* __restrict__ preQp,
    const float* __restrict__ cWhh, const float* __restrict__ pWih,
    const float* __restrict__ cbhh, const float* __restrict__ pbih,
    const float* __restrict__ Wr0, const float* __restrict__ Wr1,
    const float* __restrict__ attnW, const float* __restrict__ attnb,
    float* __restrict__ V0, float* __restrict__ V1,
    float* __restrict__ hk, float* __restrict__ Mbuf,
    float* __restrict__ GG, int* bar)
{
    const int wg = blockIdx.x;   // 128
    const int tid = threadIdx.x; // 256
    __shared__ float sm[4160];
    // CA-phase aliases (live only between the two barriers of a step)
    float* hs   = sm;            // 512
    float* v0s  = sm + 512;      // 128
    float* v1s  = sm + 640;      // 128
    float* wL0  = sm + 768;      // 128
    float* wL1  = sm + 896;      // 128
    float* part = sm + 1024;     // 256
    float* red  = sm + 1312;     // 4
    const int b  = wg >> 2;
    const int cb = wg & 3;
    // Phase-B decomposition
    const int bgrp = wg >> 5;            // 0..3  -> 8 batches
    const int cblk = wg & 31;            // 0..31 -> 96 cols
    const int r_loc = tid >> 5;          // 0..7
    const int c0 = cblk * 96 + (tid & 31) * 3;
    const float* WbaseB; const float* bbB; int crelB;
    if (c0 < 1536) { WbaseB = cWhh; bbB = cbhh; crelB = c0; }
    else           { WbaseB = pWih; bbB = pbih; crelB = c0 - 1536; }
    const float* w0B = WbaseB + (size_t)crelB * 512;

    if (wg < 32) {   // zero M parity-0 at coherence point
        stc(Mbuf + wg * 512 + tid, 0.f);
        stc(Mbuf + wg * 512 + 256 + tid, 0.f);
    }
    gridbar(bar, 128);
    for (int i = 0; i < 128; ++i) {
        const int par = i & 1;
        // ---------------- Phase B ----------------
        {
            const float* Mv = Mbuf + par * (32 * 512) + bgrp * 8 * 512;
            float tmp[16];
            #pragma unroll
            for (int u = 0; u < 16; ++u) tmp[u] = ldc(Mv + tid + u * 256);
            #pragma unroll
            for (int u = 0; u < 16; ++u) {
                const int idx = tid + u * 256;
                sm[(idx >> 9) * 516 + (idx & 511)] = tmp[u];
            }
            __syncthreads();
            float a0 = bbB[crelB], a1 = bbB[crelB + 1], a2 = bbB[crelB + 2];
            const float* mr = sm + r_loc * 516;
            const float* w1B = w0B + 512;
            const float* w2B = w0B + 1024;
            for (int k = 0; k < 512; k += 4) {
                const float4 m4 = *(const float4*)(mr + k);
                const float4 f0 = *(const float4*)(w0B + k);
                const float4 f1 = *(const float4*)(w1B + k);
                const float4 f2 = *(const float4*)(w2B + k);
                a0 += m4.x*f0.x + m4.y*f0.y + m4.z*f0.z + m4.w*f0.w;
                a1 += m4.x*f1.x + m4.y*f1.y + m4.z*f1.z + m4.w*f1.w;
                a2 += m4.x*f2.x + m4.y*f2.y + m4.z*f2.z + m4.w*f2.w;
            }
            const int rr = bgrp * 8 + r_loc;
            stc(GG + rr * 3072 + c0,     a0);
            stc(GG + rr * 3072 + c0 + 1, a1);
            stc(GG + rr * 3072 + c0 + 2, a2);
        }
        gridbar(bar, 128);
        // ---------------- Phase CA ----------------
        {
            const float* Mrow = Mbuf + par * (32 * 512) + b * 512;
            const float* pc = preQc + ((size_t)b * 128 + i) * 1536;
            const float* pp = preQp + ((size_t)b * 128 + i) * 1536;
            const float* ggb = GG + b * 3072;
            const float* q  = Hin + ((size_t)b * 128 + i) * 512;
            float hkp = 0.f;
            #pragma unroll
            for (int rep = 0; rep < 2; ++rep) {
                const int jj = tid + rep * 256;
                const float g0 = ldc(ggb + jj);
                const float g1 = ldc(ggb + 512 + jj);
                const float g2 = ldc(ggb + 1024 + jj);
                const float g3 = ldc(ggb + 1536 + jj);
                const float g4 = ldc(ggb + 2048 + jj);
                const float g5 = ldc(ggb + 2560 + jj);
                const float mv = ldc(Mrow + jj);
                const float rc = sigf(pc[jj] + g0);
                const float zc = sigf(pc[512 + jj] + g1);
                const float nc = tanhf(pc[1024 + jj] + rc * g2);
                const float oc = (1.f - zc) * nc + zc * mv;
                const float rp = sigf(g3 + pp[jj]);
                const float zp = sigf(g4 + pp[512 + jj]);
                const float np = tanhf(g5 + rp * pp[1024 + jj]);
                const float op = (1.f - zp) * np + zp * q[jj];
                const float h = oc + op;
                hs[jj] = h;
                if (cb == 0) Hout[((size_t)b * 128 + i) * 512 + jj] = h;
                hkp += h * attnW[512 + jj];
            }
            const float hk_i = blk_sum(hkp, red);
            if (cb == 0 && tid == 0) stc(hk + b * 128 + i, hk_i);
            __syncthreads();
            // V projection for this WG's 128-col slice of V0 and V1
            const int dloc = tid & 127;
            const int sel = tid >> 7;
            const int cc = cb * 128 + dloc;
            const float* wr = (sel ? Wr1 : Wr0) + (size_t)cc * 512;
            float vacc = 0.f;
            for (int k = 0; k < 512; k += 4) {
                const float4 h4 = *(const float4*)(hs + k);
                const float4 w4 = *(const float4*)(wr + k);
                vacc += h4.x*w4.x + h4.y*w4.y + h4.z*w4.z + h4.w*w4.w;
            }
            (sel ? V1 : V0)[((size_t)b * 128 + i) * 512 + cc] = vacc;  // self-read only
            if (sel) v1s[dloc] = vacc; else v0s[dloc] = vacc;
            // attention + next M
            if (i < 127) {
                const int nx = i + 1;
                const float* qn = Hin + ((size_t)b * 128 + nx) * 512;
                const float qp2 = qn[tid] * attnW[tid] + qn[tid + 256] * attnW[tid + 256];
                const float qdot = blk_sum(qp2, red) + attnb[0];
                const float* ar = adj + ((size_t)b * 128 + nx) * 128;
                float alpha = -INFINITY;
                if (tid <= i) {
                    const float hkn = (tid == i) ? hk_i : ldc(hk + b * 128 + tid);
                    alpha = qdot + hkn - (1.f - ar[tid]) * 1e30f;
                }
                const float mx = blk_max(alpha, red);
                const float e = (tid <= i) ? __expf(alpha - mx) : 0.f;
                const float esum = blk_sum(e, red);
                if (tid <= i) {
                    const float w = e / esum;
                    const float s = smk[((size_t)b * 128 + nx) * 128 + tid];
                    wL0[tid] = (s != 0.f) ? w : 0.f;
                    wL1[tid] = (s != 0.f) ? 0.f : w;
                }
                __syncthreads();
                // streamed weighted sum over n (no data-dependent pointers)
                const int half = tid >> 7;
                const float* Vb0 = V0 + ((size_t)b * 128) * 512 + cb * 128 + dloc;
                const float* Vb1 = V1 + ((size_t)b * 128) * 512 + cb * 128 + dloc;
                float acc = 0.f;
                for (int n = half; n < i; n += 2)
                    acc += wL0[n] * Vb0[(size_t)n * 512] + wL1[n] * Vb1[(size_t)n * 512];
                part[half * 128 + dloc] = acc;
                __syncthreads();
                if (tid < 128) {
                    const float m = part[tid] + part[128 + tid]
                                  + wL0[i] * v0s[tid] + wL1[i] * v1s[tid];
                    stc(Mbuf + (1 - par) * (32 * 512) + b * 512 + cb * 128 + tid, m);
                }
            }
        }
        gridbar(bar, 128);
    }
}

// ---------------------------------------------------------------------------
__global__ __launch_bounds__(256) void out_gemm(
    const float* __restrict__ x2, const float* __restrict__ W,
    const float* __restrict__ bias, float* __restrict__ out)
{
    __shared__ float xs[16 * 516];
    const int tid = threadIdx.x;
    const int r0 = blockIdx.x * 16;
    for (int idx = tid; idx < 16 * 512; idx += 256) {
        const int rr = idx >> 9, kk = idx & 511;
        xs[rr * 516 + kk] = x2[(size_t)(r0 + rr) * 512 + kk];
    }
    __syncthreads();
    if (tid < 128) {
        const int r = tid >> 3, c = tid & 7;
        if (c < 7) {
            float acc = bias[c];
            const float* wr = W + c * 512;
            const float* xr = xs + r * 516;
            for (int k = 0; k < 512; ++k) acc += xr[k] * wr[k];
            out[(size_t)(r0 + r) * 7 + c] = acc;
        }
    }
}

// ---------------------------------------------------------------------------
extern "C" void kernel_launch(void* const* d_in, const int* in_sizes, int n_in,
                              void* d_out, int out_size, void* d_ws, size_t ws_size,
                              hipStream_t stream) {
    (void)in_sizes; (void)n_in; (void)out_size; (void)ws_size;
    const float* feat     = (const float*)d_in[0];
    const float* adj      = (const float*)d_in[1];
    const float* smask    = (const float*)d_in[2];
    const float* lstm_Wih = (const float*)d_in[5];
    const float* lstm_Whh = (const float*)d_in[6];
    const float* lstm_bih = (const float*)d_in[7];
    const float* lstm_bhh = (const float*)d_in[8];
    const float* fc1_W    = (const float*)d_in[9];
    const float* fc1_b    = (const float*)d_in[10];
    const float* attn_W   = (const float*)d_in[11];
    const float* attn_b   = (const float*)d_in[12];
    const float* Wr0      = (const float*)d_in[13];
    const float* Wr1      = (const float*)d_in[14];
    const float* gruC_Wih = (const float*)d_in[15];
    const float* gruC_Whh = (const float*)d_in[16];
    const float* gruC_bih = (const float*)d_in[17];
    const float* gruC_bhh = (const float*)d_in[18];
    const float* gruP_Wih = (const float*)d_in[19];
    const float* gruP_Whh = (const float*)d_in[20];
    const float* gruP_bih = (const float*)d_in[21];
    const float* gruP_bhh = (const float*)d_in[22];
    const float* mlp0_W   = (const float*)d_in[23];
    const float* mlp0_b   = (const float*)d_in[24];
    const float* mlp1_W   = (const float*)d_in[25];
    const float* mlp1_b   = (const float*)d_in[26];
    const float* out_W    = (const float*)d_in[27];
    const float* out_b    = (const float*)d_in[28];

    float* ws       = (float*)d_ws;
    float* lstm_gi  = ws;                       // 4096*2048
    float* lstm_out = lstm_gi + 8388608;        // 4096*512
    float* H0       = lstm_out + 2097152;
    float* H1       = H0 + 2097152;
    float* H2       = H1 + 2097152;
    float* preQc    = H2 + 2097152;             // 4096*1536
    float* preQp    = preQc + 6291456;
    float* V0       = preQp + 6291456;          // 4096*512 (reused as x1)
    float* V1       = V0 + 2097152;             // (reused as x2)
    float* hkbuf    = V1 + 2097152;             // 32*128
    float* Mbuf     = hkbuf + 4096;             // 2*32*512
    float* GG       = Mbuf + 32768;             // 32*3072
    float* hbuf     = GG + 98304;               // 2*128*512
    int*   bar      = (int*)(hbuf + 131072);    // 16 ints

    const dim3 blk(256);
    init_bar<<<1, 64, 0, stream>>>(bar);

    gemm_nt<<<dim3(64, 8), blk, 0, stream>>>(feat, fc1_W, fc1_b, H0, 4096, 512, 1024, 1);
    gemm_nt<<<dim3(64, 32), blk, 0, stream>>>(feat, lstm_Wih, lstm_bih, lstm_gi, 4096, 2048, 1024, 0);
    lstm_pers<<<256, blk, 0, stream>>>(lstm_gi, lstm_Whh, lstm_bhh, hbuf, lstm_out, bar);

    for (int l = 0; l < 2; ++l) {
        const float* Hin = l ? H1 : H0;
        float* Ho = l ? H2 : H1;
        gemm_nt<<<dim3(64, 24), blk, 0, stream>>>(Hin, gruC_Wih + (size_t)l * 1536 * 512,
                                                  gruC_bih + l * 1536, preQc, 4096, 1536, 512, 0);
        gemm_nt<<<dim3(64, 24), blk, 0, stream>>>(Hin, gruP_Whh + (size_t)l * 1536 * 512,
                                                  gruP_bhh + l * 1536, preQp, 4096, 1536, 512, 0);
        gnn_layer<<<128, blk, 0, stream>>>(Hin, Ho, adj, smask, preQc, preQp,
                                           gruC_Whh + (size_t)l * 1536 * 512,
                                           gruP_Wih + (size_t)l * 1536 * 512,
                                           gruC_bhh + l * 1536, gruP_bih + l * 1536,
                                           Wr0 + (size_t)l * 512 * 512,
                                           Wr1 + (size_t)l * 512 * 512,
                                           attn_W + l * 1024, attn_b + l,
                                           V0, V1, hkbuf, Mbuf, GG, bar + 4 + l * 4);
    }

    float* x1 = V0;
    float* x2 = V1;
    gemm_cat<<<dim3(64, 8), blk, 0, stream>>>(H0, H1, H2, feat, lstm_out, mlp0_W, mlp0_b, x1);
    gemm_nt<<<dim3(64, 8), blk, 0, stream>>>(x1, mlp1_W, mlp1_b, x2, 4096, 512, 512, 1);
    out_gemm<<<256, blk, 0, stream>>>(x2, out_W, out_b, (float*)d_out);
}

// Round 3
// 14032.520 us; speedup vs baseline: 2.0307x; 1.5411x over previous
//
#include <hip/hip_runtime.h>
#include <math.h>

// Sizes: B=32, N=128, EMB=1024, HID=512, L=2, NCLS=7, IN_DIM=3072, TOK=4096
// Structure: per-step graph kernels (no persistent grids, no device barriers,
// no sc1). Kernel boundaries provide cross-XCD ordering/coherence.

__device__ __forceinline__ float sigf(float x) { return 1.f / (1.f + __expf(-x)); }

__device__ __forceinline__ float blk_sum(float v, float* red) {
    #pragma unroll
    for (int o = 32; o > 0; o >>= 1) v += __shfl_down(v, o, 64);
    const int lane = threadIdx.x & 63, wid = threadIdx.x >> 6;
    __syncthreads();
    if (lane == 0) red[wid] = v;
    __syncthreads();
    return (red[0] + red[1]) + (red[2] + red[3]);
}
__device__ __forceinline__ float blk_max(float v, float* red) {
    #pragma unroll
    for (int o = 32; o > 0; o >>= 1) v = fmaxf(v, __shfl_down(v, o, 64));
    const int lane = threadIdx.x & 63, wid = threadIdx.x >> 6;
    __syncthreads();
    if (lane == 0) red[wid] = v;
    __syncthreads();
    return fmaxf(fmaxf(red[0], red[1]), fmaxf(red[2], red[3]));
}

// ---------------------------------------------------------------------------
// Generic fp32 GEMM: C = act(A[M,K] @ W[N,K]^T + bias). 64x64 tile.
// ---------------------------------------------------------------------------
__global__ __launch_bounds__(256) void gemm_nt(
    const float* __restrict__ A, const float* __restrict__ W,
    const float* __restrict__ bias, float* __restrict__ C,
    int M, int N, int K, int relu)
{
    __shared__ float As[16][68];
    __shared__ float Ws[16][68];
    const int tid = threadIdx.x;
    const int m0 = blockIdx.x * 64;
    const int n0 = blockIdx.y * 64;
    const int lr = tid >> 2;
    const int lk = (tid & 3) << 2;
    const int tm = (tid & 15) << 2;
    const int tn = (tid >> 4) << 2;
    float acc[4][4] = {};
    const float* Aptr = A + (size_t)(m0 + lr) * K + lk;
    const float* Wptr = W + (size_t)(n0 + lr) * K + lk;
    for (int k0 = 0; k0 < K; k0 += 16) {
        __syncthreads();
        const float4 av = *(const float4*)(Aptr + k0);
        const float4 wv = *(const float4*)(Wptr + k0);
        As[lk + 0][lr] = av.x; As[lk + 1][lr] = av.y;
        As[lk + 2][lr] = av.z; As[lk + 3][lr] = av.w;
        Ws[lk + 0][lr] = wv.x; Ws[lk + 1][lr] = wv.y;
        Ws[lk + 2][lr] = wv.z; Ws[lk + 3][lr] = wv.w;
        __syncthreads();
        #pragma unroll
        for (int kk = 0; kk < 16; ++kk) {
            float a[4], b[4];
            #pragma unroll
            for (int u = 0; u < 4; ++u) { a[u] = As[kk][tm + u]; b[u] = Ws[kk][tn + u]; }
            #pragma unroll
            for (int ii = 0; ii < 4; ++ii)
                #pragma unroll
                for (int jj = 0; jj < 4; ++jj)
                    acc[ii][jj] += a[ii] * b[jj];
        }
    }
    #pragma unroll
    for (int ii = 0; ii < 4; ++ii)
        #pragma unroll
        for (int jj = 0; jj < 4; ++jj) {
            float v = acc[ii][jj] + bias[n0 + tn + jj];
            if (relu) v = fmaxf(v, 0.f);
            C[(size_t)(m0 + tm + ii) * N + n0 + tn + jj] = v;
        }
}

// ---------------------------------------------------------------------------
// mlp0 with fused 5-way concat
// ---------------------------------------------------------------------------
__global__ __launch_bounds__(256) void gemm_cat(
    const float* __restrict__ H0, const float* __restrict__ H1,
    const float* __restrict__ H2, const float* __restrict__ feat,
    const float* __restrict__ lstm, const float* __restrict__ W,
    const float* __restrict__ bias, float* __restrict__ C)
{
    __shared__ float As[16][68];
    __shared__ float Ws[16][68];
    const int tid = threadIdx.x;
    const int m0 = blockIdx.x * 64;
    const int n0 = blockIdx.y * 64;
    const int lr = tid >> 2;
    const int lk = (tid & 3) << 2;
    const int tm = (tid & 15) << 2;
    const int tn = (tid >> 4) << 2;
    float acc[4][4] = {};
    for (int k0 = 0; k0 < 3072; k0 += 16) {
        const float* src; int kloc, Kp;
        if (k0 < 512)       { src = H0;   kloc = k0;        Kp = 512;  }
        else if (k0 < 1024) { src = H1;   kloc = k0 - 512;  Kp = 512;  }
        else if (k0 < 1536) { src = H2;   kloc = k0 - 1024; Kp = 512;  }
        else if (k0 < 2560) { src = feat; kloc = k0 - 1536; Kp = 1024; }
        else                { src = lstm; kloc = k0 - 2560; Kp = 512;  }
        __syncthreads();
        const float4 av = *(const float4*)(src + (size_t)(m0 + lr) * Kp + kloc + lk);
        const float4 wv = *(const float4*)(W + (size_t)(n0 + lr) * 3072 + k0 + lk);
        As[lk + 0][lr] = av.x; As[lk + 1][lr] = av.y;
        As[lk + 2][lr] = av.z; As[lk + 3][lr] = av.w;
        Ws[lk + 0][lr] = wv.x; Ws[lk + 1][lr] = wv.y;
        Ws[lk + 2][lr] = wv.z; Ws[lk + 3][lr] = wv.w;
        __syncthreads();
        #pragma unroll
        for (int kk = 0; kk < 16; ++kk) {
            float a[4], b[4];
            #pragma unroll
            for (int u = 0; u < 4; ++u) { a[u] = As[kk][tm + u]; b[u] = Ws[kk][tn + u]; }
            #pragma unroll
            for (int ii = 0; ii < 4; ++ii)
                #pragma unroll
                for (int jj = 0; jj < 4; ++jj)
                    acc[ii][jj] += a[ii] * b[jj];
        }
    }
    #pragma unroll
    for (int ii = 0; ii < 4; ++ii)
        #pragma unroll
        for (int jj = 0; jj < 4; ++jj) {
            float v = fmaxf(acc[ii][jj] + bias[n0 + tn + jj], 0.f);
            C[(size_t)(m0 + tm + ii) * 512 + n0 + tn + jj] = v;
        }
}

// ---------------------------------------------------------------------------
// One LSTM time step, fused GEMM + gates. Grid (8 rowblocks, 16 hidblocks),
// 256 thr. Thread (j=tid>>3, r8=tid&7): 2 rows x 1 hid x 4 gates.
// c is thread-exclusive (in-place); h double-buffered across launches.
// ---------------------------------------------------------------------------
__global__ __launch_bounds__(256) void lstm_step(
    const int t,
    const float* __restrict__ gi, const float* __restrict__ Whh,
    const float* __restrict__ bhh,
    const float* __restrict__ h_in, float* __restrict__ h_out,
    float* __restrict__ c, float* __restrict__ ys)
{
    const int tid = threadIdx.x;
    const int rb = blockIdx.x;   // 0..7
    const int hb = blockIdx.y;   // 0..15
    const int j  = tid >> 3;     // 0..31
    const int r8 = tid & 7;      // 0..7
    const int ghid = hb * 32 + j;
    const int row0 = rb * 16 + r8;   // second row = row0 + 8
    __shared__ float hs[16 * 520];
    float s[2][4];
    #pragma unroll
    for (int g = 0; g < 4; ++g) {
        const float bb = bhh[g * 512 + ghid];
        s[0][g] = bb + gi[((size_t)t * 128 + row0) * 2048 + g * 512 + ghid];
        s[1][g] = bb + gi[((size_t)t * 128 + row0 + 8) * 2048 + g * 512 + ghid];
    }
    if (t > 0) {
        for (int idx = tid; idx < 16 * 128; idx += 256) {
            const int r = idx >> 7, k4 = (idx & 127) << 2;
            *(float4*)(hs + r * 520 + k4) =
                *(const float4*)(h_in + (size_t)(rb * 16 + r) * 512 + k4);
        }
        __syncthreads();
        const float* w0 = Whh + (size_t)(0 * 512 + ghid) * 512;
        const float* w1 = Whh + (size_t)(1 * 512 + ghid) * 512;
        const float* w2 = Whh + (size_t)(2 * 512 + ghid) * 512;
        const float* w3 = Whh + (size_t)(3 * 512 + ghid) * 512;
        const float* h0 = hs + r8 * 520;
        const float* h1 = hs + (r8 + 8) * 520;
        for (int k = 0; k < 512; k += 4) {
            const float4 a  = *(const float4*)(h0 + k);
            const float4 b  = *(const float4*)(h1 + k);
            const float4 wi = *(const float4*)(w0 + k);
            const float4 wf = *(const float4*)(w1 + k);
            const float4 wg = *(const float4*)(w2 + k);
            const float4 wo = *(const float4*)(w3 + k);
            s[0][0] += a.x*wi.x + a.y*wi.y + a.z*wi.z + a.w*wi.w;
            s[0][1] += a.x*wf.x + a.y*wf.y + a.z*wf.z + a.w*wf.w;
            s[0][2] += a.x*wg.x + a.y*wg.y + a.z*wg.z + a.w*wg.w;
            s[0][3] += a.x*wo.x + a.y*wo.y + a.z*wo.z + a.w*wo.w;
            s[1][0] += b.x*wi.x + b.y*wi.y + b.z*wi.z + b.w*wi.w;
            s[1][1] += b.x*wf.x + b.y*wf.y + b.z*wf.z + b.w*wf.w;
            s[1][2] += b.x*wg.x + b.y*wg.y + b.z*wg.z + b.w*wg.w;
            s[1][3] += b.x*wo.x + b.y*wo.y + b.z*wo.z + b.w*wo.w;
        }
    }
    #pragma unroll
    for (int u = 0; u < 2; ++u) {
        const int row = row0 + u * 8;
        const size_t off = (size_t)row * 512 + ghid;
        const float cp = (t > 0) ? c[off] : 0.f;
        const float cn = sigf(s[u][1]) * cp + sigf(s[u][0]) * tanhf(s[u][2]);
        const float hn = sigf(s[u][3]) * tanhf(cn);
        c[off] = cn;
        h_out[off] = hn;
        ys[((size_t)t * 128 + row) * 512 + ghid] = hn;
    }
}

// ---------------------------------------------------------------------------
// GNN phase B, one step: GG[32,3072] = M[32,512] @ [cWhh|pWih]^T + [cbhh|pbih]
// Grid 96 WGs x 32 cols. M staged to LDS; weight rows streamed (L2/LIC).
// Thread (c=tid&31, rg=tid>>5): col wg*32+c, rows rg*4..+4. 2048 FMA/thread.
// ---------------------------------------------------------------------------
__global__ __launch_bounds__(256) void gnn_b(
    const float* __restrict__ Min,
    const float* __restrict__ cWhh, const float* __restrict__ pWih,
    const float* __restrict__ cbhh, const float* __restrict__ pbih,
    float* __restrict__ GG)
{
    __shared__ float Ms[32 * 520];
    const int tid = threadIdx.x;
    for (int idx = tid; idx < 4096; idx += 256) {
        const int r = idx >> 7, k4 = (idx & 127) << 2;
        *(float4*)(Ms + r * 520 + k4) = *(const float4*)(Min + (size_t)r * 512 + k4);
    }
    __syncthreads();
    const int c  = tid & 31;
    const int rg = tid >> 5;          // 0..7
    const int colg = blockIdx.x * 32 + c;
    const float* wrow = (colg < 1536) ? cWhh + (size_t)colg * 512
                                      : pWih + (size_t)(colg - 1536) * 512;
    const float bias = (colg < 1536) ? cbhh[colg] : pbih[colg - 1536];
    const float* m0 = Ms + (rg * 4 + 0) * 520;
    const float* m1 = Ms + (rg * 4 + 1) * 520;
    const float* m2 = Ms + (rg * 4 + 2) * 520;
    const float* m3 = Ms + (rg * 4 + 3) * 520;
    float a0 = 0.f, a1 = 0.f, a2 = 0.f, a3 = 0.f;
    for (int k = 0; k < 512; k += 4) {
        const float4 w  = *(const float4*)(wrow + k);
        const float4 v0 = *(const float4*)(m0 + k);
        const float4 v1 = *(const float4*)(m1 + k);
        const float4 v2 = *(const float4*)(m2 + k);
        const float4 v3 = *(const float4*)(m3 + k);
        a0 += v0.x*w.x + v0.y*w.y + v0.z*w.z + v0.w*w.w;
        a1 += v1.x*w.x + v1.y*w.y + v1.z*w.z + v1.w*w.w;
        a2 += v2.x*w.x + v2.y*w.y + v2.z*w.z + v2.w*w.w;
        a3 += v3.x*w.x + v3.y*w.y + v3.z*w.z + v3.w*w.w;
    }
    GG[(size_t)(rg * 4 + 0) * 3072 + colg] = a0 + bias;
    GG[(size_t)(rg * 4 + 1) * 3072 + colg] = a1 + bias;
    GG[(size_t)(rg * 4 + 2) * 3072 + colg] = a2 + bias;
    GG[(size_t)(rg * 4 + 3) * 3072 + colg] = a3 + bias;
}

// ---------------------------------------------------------------------------
// GNN phase CA, one step i. Grid 128 WGs (b=wg>>2, cb=wg&3), 256 thr.
// gates -> h (redundant per cb); hk; V0/V1 128-col slice; softmax(i+1);
// M(i+1) col-slice into Mout (double-buffered by host).
// ---------------------------------------------------------------------------
__global__ __launch_bounds__(256) void gnn_ca(
    const int i,
    const float* __restrict__ Hin, float* __restrict__ Hout,
    const float* __restrict__ adj, const float* __restrict__ smk,
    const float* __restrict__ preQc, const float* __restrict__ preQp,
    const float* __restrict__ Wr0, const float* __restrict__ Wr1,
    const float* __restrict__ attnW, const float* __restrict__ attnb,
    float* __restrict__ V0, float* __restrict__ V1,
    float* __restrict__ hk, const float* __restrict__ Min,
    float* __restrict__ Mout, const float* __restrict__ GG)
{
    const int wg = blockIdx.x;
    const int tid = threadIdx.x;
    __shared__ float sm[1440];
    float* hs   = sm;            // 512
    float* v0s  = sm + 512;      // 128
    float* v1s  = sm + 640;      // 128
    float* wL0  = sm + 768;      // 128
    float* wL1  = sm + 896;      // 128
    float* part = sm + 1024;     // 256
    float* red  = sm + 1280;     // 4
    const int b  = wg >> 2;
    const int cb = wg & 3;
    const float* Mrow = Min + (size_t)b * 512;
    const float* pc = preQc + ((size_t)b * 128 + i) * 1536;
    const float* pp = preQp + ((size_t)b * 128 + i) * 1536;
    const float* ggb = GG + (size_t)b * 3072;
    const float* q  = Hin + ((size_t)b * 128 + i) * 512;
    float hkp = 0.f;
    #pragma unroll
    for (int rep = 0; rep < 2; ++rep) {
        const int jj = tid + rep * 256;
        const float rc = sigf(pc[jj] + ggb[jj]);
        const float zc = sigf(pc[512 + jj] + ggb[512 + jj]);
        const float nc = tanhf(pc[1024 + jj] + rc * ggb[1024 + jj]);
        const float oc = (1.f - zc) * nc + zc * Mrow[jj];
        const float rp = sigf(ggb[1536 + jj] + pp[jj]);
        const float zp = sigf(ggb[2048 + jj] + pp[512 + jj]);
        const float np = tanhf(ggb[2560 + jj] + rp * pp[1024 + jj]);
        const float op = (1.f - zp) * np + zp * q[jj];
        const float h = oc + op;
        hs[jj] = h;
        if (cb == 0) Hout[((size_t)b * 128 + i) * 512 + jj] = h;
        hkp += h * attnW[512 + jj];
    }
    const float hk_i = blk_sum(hkp, red);
    if (cb == 0 && tid == 0) hk[b * 128 + i] = hk_i;
    __syncthreads();
    // V projection for this WG's 128-col slice of V0 and V1
    const int dloc = tid & 127;
    const int sel = tid >> 7;
    const int cc = cb * 128 + dloc;
    const float* wr = (sel ? Wr1 : Wr0) + (size_t)cc * 512;
    float vacc = 0.f;
    for (int k = 0; k < 512; k += 4) {
        const float4 h4 = *(const float4*)(hs + k);
        const float4 w4 = *(const float4*)(wr + k);
        vacc += h4.x*w4.x + h4.y*w4.y + h4.z*w4.z + h4.w*w4.w;
    }
    (sel ? V1 : V0)[((size_t)b * 128 + i) * 512 + cc] = vacc;
    if (sel) v1s[dloc] = vacc; else v0s[dloc] = vacc;
    // attention softmax for step i+1 and M(i+1)
    if (i < 127) {
        const int nx = i + 1;
        const float* qn = Hin + ((size_t)b * 128 + nx) * 512;
        const float qp2 = qn[tid] * attnW[tid] + qn[tid + 256] * attnW[tid + 256];
        const float qdot = blk_sum(qp2, red) + attnb[0];
        const float* ar = adj + ((size_t)b * 128 + nx) * 128;
        float alpha = -INFINITY;
        if (tid <= i) {
            const float hkn = (tid == i) ? hk_i : hk[b * 128 + tid];
            alpha = qdot + hkn - (1.f - ar[tid]) * 1e30f;
        }
        const float mx = blk_max(alpha, red);
        const float e = (tid <= i) ? __expf(alpha - mx) : 0.f;
        const float esum = blk_sum(e, red);
        if (tid <= i) {
            const float w = e / esum;
            const float s = smk[((size_t)b * 128 + nx) * 128 + tid];
            wL0[tid] = (s != 0.f) ? w : 0.f;
            wL1[tid] = (s != 0.f) ? 0.f : w;
        }
        __syncthreads();
        const int half = tid >> 7;
        const float* Vb0 = V0 + ((size_t)b * 128) * 512 + cb * 128 + dloc;
        const float* Vb1 = V1 + ((size_t)b * 128) * 512 + cb * 128 + dloc;
        float acc = 0.f;
        for (int n = half; n < i; n += 2)
            acc += wL0[n] * Vb0[(size_t)n * 512] + wL1[n] * Vb1[(size_t)n * 512];
        part[half * 128 + dloc] = acc;
        __syncthreads();
        if (tid < 128) {
            const float m = part[tid] + part[128 + tid]
                          + wL0[i] * v0s[tid] + wL1[i] * v1s[tid];
            Mout[(size_t)b * 512 + cb * 128 + tid] = m;
        }
    }
}

// ---------------------------------------------------------------------------
__global__ __launch_bounds__(256) void out_gemm(
    const float* __restrict__ x2, const float* __restrict__ W,
    const float* __restrict__ bias, float* __restrict__ out)
{
    __shared__ float xs[16 * 516];
    const int tid = threadIdx.x;
    const int r0 = blockIdx.x * 16;
    for (int idx = tid; idx < 16 * 512; idx += 256) {
        const int rr = idx >> 9, kk = idx & 511;
        xs[rr * 516 + kk] = x2[(size_t)(r0 + rr) * 512 + kk];
    }
    __syncthreads();
    if (tid < 128) {
        const int r = tid >> 3, c = tid & 7;
        if (c < 7) {
            float acc = bias[c];
            const float* wr = W + c * 512;
            const float* xr = xs + r * 516;
            for (int k = 0; k < 512; ++k) acc += xr[k] * wr[k];
            out[(size_t)(r0 + r) * 7 + c] = acc;
        }
    }
}

// ---------------------------------------------------------------------------
extern "C" void kernel_launch(void* const* d_in, const int* in_sizes, int n_in,
                              void* d_out, int out_size, void* d_ws, size_t ws_size,
                              hipStream_t stream) {
    (void)in_sizes; (void)n_in; (void)out_size; (void)ws_size;
    const float* feat     = (const float*)d_in[0];
    const float* adj      = (const float*)d_in[1];
    const float* smask    = (const float*)d_in[2];
    const float* lstm_Wih = (const float*)d_in[5];
    const float* lstm_Whh = (const float*)d_in[6];
    const float* lstm_bih = (const float*)d_in[7];
    const float* lstm_bhh = (const float*)d_in[8];
    const float* fc1_W    = (const float*)d_in[9];
    const float* fc1_b    = (const float*)d_in[10];
    const float* attn_W   = (const float*)d_in[11];
    const float* attn_b   = (const float*)d_in[12];
    const float* Wr0      = (const float*)d_in[13];
    const float* Wr1      = (const float*)d_in[14];
    const float* gruC_Wih = (const float*)d_in[15];
    const float* gruC_Whh = (const float*)d_in[16];
    const float* gruC_bih = (const float*)d_in[17];
    const float* gruC_bhh = (const float*)d_in[18];
    const float* gruP_Wih = (const float*)d_in[19];
    const float* gruP_Whh = (const float*)d_in[20];
    const float* gruP_bih = (const float*)d_in[21];
    const float* gruP_bhh = (const float*)d_in[22];
    const float* mlp0_W   = (const float*)d_in[23];
    const float* mlp0_b   = (const float*)d_in[24];
    const float* mlp1_W   = (const float*)d_in[25];
    const float* mlp1_b   = (const float*)d_in[26];
    const float* out_W    = (const float*)d_in[27];
    const float* out_b    = (const float*)d_in[28];

    float* ws       = (float*)d_ws;
    float* lstm_gi  = ws;                       // 4096*2048
    float* lstm_out = lstm_gi + 8388608;        // 4096*512
    float* H0       = lstm_out + 2097152;
    float* H1       = H0 + 2097152;
    float* H2       = H1 + 2097152;
    float* preQc    = H2 + 2097152;             // 4096*1536
    float* preQp    = preQc + 6291456;
    float* V0       = preQp + 6291456;          // 4096*512 (reused as x1)
    float* V1       = V0 + 2097152;             // (reused as x2)
    float* hkbuf    = V1 + 2097152;             // 32*128
    float* Mbuf     = hkbuf + 4096;             // 2*32*512
    float* GG       = Mbuf + 32768;             // 32*3072
    float* hbuf     = GG + 98304;               // 2*128*512
    float* cbuf     = hbuf + 131072;            // 128*512

    const dim3 blk(256);

    // H0 = relu(feat @ fc1^T + b); lstm_gi = feat @ lstm_Wih^T + bih
    gemm_nt<<<dim3(64, 8), blk, 0, stream>>>(feat, fc1_W, fc1_b, H0, 4096, 512, 1024, 1);
    gemm_nt<<<dim3(64, 32), blk, 0, stream>>>(feat, lstm_Wih, lstm_bih, lstm_gi, 4096, 2048, 1024, 0);

    // LSTM scan: one kernel per time step
    for (int t = 0; t < 32; ++t) {
        float* h_in  = hbuf + (size_t)(t & 1) * 65536;
        float* h_out = hbuf + (size_t)((t + 1) & 1) * 65536;
        lstm_step<<<dim3(8, 16), blk, 0, stream>>>(t, lstm_gi, lstm_Whh, lstm_bhh,
                                                   h_in, h_out, cbuf, lstm_out);
    }

    for (int l = 0; l < 2; ++l) {
        const float* Hin = l ? H1 : H0;
        float* Ho = l ? H2 : H1;
        const float* cWhh = gruC_Whh + (size_t)l * 1536 * 512;
        const float* pWih = gruP_Wih + (size_t)l * 1536 * 512;
        const float* cbhh = gruC_bhh + l * 1536;
        const float* pbih = gruP_bih + l * 1536;
        gemm_nt<<<dim3(64, 24), blk, 0, stream>>>(Hin, gruC_Wih + (size_t)l * 1536 * 512,
                                                  gruC_bih + l * 1536, preQc, 4096, 1536, 512, 0);
        gemm_nt<<<dim3(64, 24), blk, 0, stream>>>(Hin, gruP_Whh + (size_t)l * 1536 * 512,
                                                  gruP_bhh + l * 1536, preQp, 4096, 1536, 512, 0);
        hipMemsetAsync(Mbuf, 0, 16384 * sizeof(float), stream);  // M(0) = 0 (parity 0)
        for (int i = 0; i < 128; ++i) {
            float* Min  = Mbuf + (size_t)(i & 1) * 16384;
            float* Mout = Mbuf + (size_t)((i + 1) & 1) * 16384;
            gnn_b<<<96, blk, 0, stream>>>(Min, cWhh, pWih, cbhh, pbih, GG);
            gnn_ca<<<128, blk, 0, stream>>>(i, Hin, Ho, adj, smask, preQc, preQp,
                                            Wr0 + (size_t)l * 512 * 512,
                                            Wr1 + (size_t)l * 512 * 512,
                                            attn_W + l * 1024, attn_b + l,
                                            V0, V1, hkbuf, Min, Mout, GG);
        }
    }

    float* x1 = V0;
    float* x2 = V1;
    gemm_cat<<<dim3(64, 8), blk, 0, stream>>>(H0, H1, H2, feat, lstm_out, mlp0_W, mlp0_b, x1);
    gemm_nt<<<dim3(64, 8), blk, 0, stream>>>(x1, mlp1_W, mlp1_b, x2, 4096, 512, 512, 1);
    out_gemm<<<256, blk, 0, stream>>>(x2, out_W, out_b, (float*)d_out);
}

// Round 5
// 13528.290 us; speedup vs baseline: 2.1064x; 1.0373x over previous
//
#include <hip/hip_runtime.h>
#include <math.h>

// Sizes: B=32, N=128, EMB=1024, HID=512, L=2, NCLS=7, IN_DIM=3072, TOK=4096
// Design: one persistent kernel; 8 GNN pods (16 WGs, 4 batches each) + 8 LSTM
// row-pods (16 WGs, 16 rows each). Pod-local barriers only (16 arrivals).
// Coherence contract: ALL cross-WG data is written with stc() (sc1 store) and
// read with ldc() (sc1 load). Same-WG and cross-kernel data may use plain ops.

#define AGENT __HIP_MEMORY_SCOPE_AGENT

__device__ __forceinline__ float ldc(const float* p) {
    return __hip_atomic_load(p, __ATOMIC_RELAXED, AGENT);
}
__device__ __forceinline__ void stc(float* p, float v) {
    __hip_atomic_store(p, v, __ATOMIC_RELAXED, AGENT);
}

// Pod barrier (sense/generation). __syncthreads drains vmcnt before arrival.
__device__ __forceinline__ void podbar(int* bar, int nwg) {
    __syncthreads();
    if (threadIdx.x == 0) {
        int g = __hip_atomic_load(bar + 1, __ATOMIC_RELAXED, AGENT);
        int v = __hip_atomic_fetch_add(bar, 1, __ATOMIC_RELAXED, AGENT);
        if (v == nwg - 1) {
            __hip_atomic_store(bar, 0, __ATOMIC_RELAXED, AGENT);
            __builtin_amdgcn_s_waitcnt(0);
            __hip_atomic_store(bar + 1, g + 1, __ATOMIC_RELAXED, AGENT);
        } else {
            while (__hip_atomic_load(bar + 1, __ATOMIC_RELAXED, AGENT) == g) {
                __builtin_amdgcn_s_sleep(1);
            }
        }
        __asm__ __volatile__("" ::: "memory");
    }
    __syncthreads();
}

__global__ void init_bar(int* bar) { bar[threadIdx.x] = 0; }

__device__ __forceinline__ float sigf(float x) { return 1.f / (1.f + __expf(-x)); }

__device__ __forceinline__ float blk_sum(float v, float* red) {
    #pragma unroll
    for (int o = 32; o > 0; o >>= 1) v += __shfl_down(v, o, 64);
    const int lane = threadIdx.x & 63, wid = threadIdx.x >> 6;
    __syncthreads();
    if (lane == 0) red[wid] = v;
    __syncthreads();
    return (red[0] + red[1]) + (red[2] + red[3]);
}
__device__ __forceinline__ float blk_max(float v, float* red) {
    #pragma unroll
    for (int o = 32; o > 0; o >>= 1) v = fmaxf(v, __shfl_down(v, o, 64));
    const int lane = threadIdx.x & 63, wid = threadIdx.x >> 6;
    __syncthreads();
    if (lane == 0) red[wid] = v;
    __syncthreads();
    return fmaxf(fmaxf(red[0], red[1]), fmaxf(red[2], red[3]));
}

// ---------------------------------------------------------------------------
// Generic fp32 GEMM: C = act(A[M,K] @ W[N,K]^T + bias). 64x64 tile.
// ---------------------------------------------------------------------------
__global__ __launch_bounds__(256) void gemm_nt(
    const float* __restrict__ A, const float* __restrict__ W,
    const float* __restrict__ bias, float* __restrict__ C,
    int M, int N, int K, int relu)
{
    __shared__ float As[16][68];
    __shared__ float Ws[16][68];
    const int tid = threadIdx.x;
    const int m0 = blockIdx.x * 64;
    const int n0 = blockIdx.y * 64;
    const int lr = tid >> 2;
    const int lk = (tid & 3) << 2;
    const int tm = (tid & 15) << 2;
    const int tn = (tid >> 4) << 2;
    float acc[4][4] = {};
    const float* Aptr = A + (size_t)(m0 + lr) * K + lk;
    const float* Wptr = W + (size_t)(n0 + lr) * K + lk;
    for (int k0 = 0; k0 < K; k0 += 16) {
        __syncthreads();
        const float4 av = *(const float4*)(Aptr + k0);
        const float4 wv = *(const float4*)(Wptr + k0);
        As[lk + 0][lr] = av.x; As[lk + 1][lr] = av.y;
        As[lk + 2][lr] = av.z; As[lk + 3][lr] = av.w;
        Ws[lk + 0][lr] = wv.x; Ws[lk + 1][lr] = wv.y;
        Ws[lk + 2][lr] = wv.z; Ws[lk + 3][lr] = wv.w;
        __syncthreads();
        #pragma unroll
        for (int kk = 0; kk < 16; ++kk) {
            float a[4], b[4];
            #pragma unroll
            for (int u = 0; u < 4; ++u) { a[u] = As[kk][tm + u]; b[u] = Ws[kk][tn + u]; }
            #pragma unroll
            for (int ii = 0; ii < 4; ++ii)
                #pragma unroll
                for (int jj = 0; jj < 4; ++jj)
                    acc[ii][jj] += a[ii] * b[jj];
        }
    }
    #pragma unroll
    for (int ii = 0; ii < 4; ++ii)
        #pragma unroll
        for (int jj = 0; jj < 4; ++jj) {
            float v = acc[ii][jj] + bias[n0 + tn + jj];
            if (relu) v = fmaxf(v, 0.f);
            C[(size_t)(m0 + tm + ii) * N + n0 + tn + jj] = v;
        }
}

// ---------------------------------------------------------------------------
// mlp0 with fused 5-way concat
// ---------------------------------------------------------------------------
__global__ __launch_bounds__(256) void gemm_cat(
    const float* __restrict__ H0, const float* __restrict__ H1,
    const float* __restrict__ H2, const float* __restrict__ feat,
    const float* __restrict__ lstm, const float* __restrict__ W,
    const float* __restrict__ bias, float* __restrict__ C)
{
    __shared__ float As[16][68];
    __shared__ float Ws[16][68];
    const int tid = threadIdx.x;
    const int m0 = blockIdx.x * 64;
    const int n0 = blockIdx.y * 64;
    const int lr = tid >> 2;
    const int lk = (tid & 3) << 2;
    const int tm = (tid & 15) << 2;
    const int tn = (tid >> 4) << 2;
    float acc[4][4] = {};
    for (int k0 = 0; k0 < 3072; k0 += 16) {
        const float* src; int kloc, Kp;
        if (k0 < 512)       { src = H0;   kloc = k0;        Kp = 512;  }
        else if (k0 < 1024) { src = H1;   kloc = k0 - 512;  Kp = 512;  }
        else if (k0 < 1536) { src = H2;   kloc = k0 - 1024; Kp = 512;  }
        else if (k0 < 2560) { src = feat; kloc = k0 - 1536; Kp = 1024; }
        else                { src = lstm; kloc = k0 - 2560; Kp = 512;  }
        __syncthreads();
        const float4 av = *(const float4*)(src + (size_t)(m0 + lr) * Kp + kloc + lk);
        const float4 wv = *(const float4*)(W + (size_t)(n0 + lr) * 3072 + k0 + lk);
        As[lk + 0][lr] = av.x; As[lk + 1][lr] = av.y;
        As[lk + 2][lr] = av.z; As[lk + 3][lr] = av.w;
        Ws[lk + 0][lr] = wv.x; Ws[lk + 1][lr] = wv.y;
        Ws[lk + 2][lr] = wv.z; Ws[lk + 3][lr] = wv.w;
        __syncthreads();
        #pragma unroll
        for (int kk = 0; kk < 16; ++kk) {
            float a[4], b[4];
            #pragma unroll
            for (int u = 0; u < 4; ++u) { a[u] = As[kk][tm + u]; b[u] = Ws[kk][tn + u]; }
            #pragma unroll
            for (int ii = 0; ii < 4; ++ii)
                #pragma unroll
                for (int jj = 0; jj < 4; ++jj)
                    acc[ii][jj] += a[ii] * b[jj];
        }
    }
    #pragma unroll
    for (int ii = 0; ii < 4; ++ii)
        #pragma unroll
        for (int jj = 0; jj < 4; ++jj) {
            float v = fmaxf(acc[ii][jj] + bias[n0 + tn + jj], 0.f);
            C[(size_t)(m0 + tm + ii) * 512 + n0 + tn + jj] = v;
        }
}

// ---------------------------------------------------------------------------
// Transpose with 2-source concat: dst[k][col] = src(col)[k], k<512.
// ---------------------------------------------------------------------------
__global__ __launch_bounds__(256) void tpose_cat(
    const float* __restrict__ src0, const float* __restrict__ src1,
    float* __restrict__ dst, int nsplit, int ncol)
{
    __shared__ float t[64][65];
    const int tid = threadIdx.x;
    const int c0 = blockIdx.x * 64;
    const int k0 = blockIdx.y * 64;
    for (int idx = tid; idx < 4096; idx += 256) {
        const int r = idx >> 6, c = idx & 63;
        const int col = c0 + r;
        const float* srow = (col < nsplit) ? src0 + (size_t)col * 512
                                           : src1 + (size_t)(col - nsplit) * 512;
        t[r][c] = srow[k0 + c];
    }
    __syncthreads();
    for (int idx = tid; idx < 4096; idx += 256) {
        const int k = idx >> 6, c = idx & 63;
        dst[(size_t)(k0 + k) * ncol + c0 + c] = t[c][k];
    }
}

// ---------------------------------------------------------------------------
// Fused persistent kernel: 256 WGs.
//   WG 0..127  : GNN pods (pod = wg>>4, 16 WGs, 4 batches), layers 0 and 1,
//                with in-pod layer-1 preQ GEMM between layers (A read from H1
//                via ldc — coherent; NO plain-store staging buffer).
//   WG 128..255: LSTM row-pods (pod = (wg-128)>>4, 16 rows), 32 steps, exit.
// ---------------------------------------------------------------------------
__global__ __launch_bounds__(256, 1) void fused_pers(
    const float* __restrict__ H0, float* __restrict__ H1, float* __restrict__ H2,
    const float* __restrict__ adj, const float* __restrict__ smk,
    float* __restrict__ preQc, float* __restrict__ preQp,
    const float* __restrict__ WtB, const float* __restrict__ WrT,
    const float* __restrict__ cbhh_all, const float* __restrict__ pbih_all,
    const float* __restrict__ attnW_all, const float* __restrict__ attnb_all,
    const float* __restrict__ cWih1, const float* __restrict__ cbih1,
    const float* __restrict__ pWhh1, const float* __restrict__ pbhh1,
    float* __restrict__ V0, float* __restrict__ V1,
    float* __restrict__ hk, float* __restrict__ Mbuf, float* __restrict__ Mtbuf,
    float* __restrict__ GG,
    const float* __restrict__ gi, const float* __restrict__ Whh,
    const float* __restrict__ bhh, float* __restrict__ hbuf,
    float* __restrict__ lstm_out, int* __restrict__ bar)
{
    __shared__ float smem[8448];
    const int wg = blockIdx.x;
    const int tid = threadIdx.x;

    if (wg >= 128) {
        // =========================== LSTM pods ===========================
        const int lwg = wg - 128;
        const int lp = lwg >> 4;
        const int lw = lwg & 15;
        int* pbar = bar + (8 + lp) * 64;
        const int r0 = lp * 16;
        const int j  = tid >> 3;          // 0..31
        const int r2 = tid & 7;           // 0..7
        const int ghid = lw * 32 + j;
        const float* W0 = Whh + (size_t)ghid * 512;
        const float* W1 = Whh + (size_t)(512 + ghid) * 512;
        const float* W2 = Whh + (size_t)(1024 + ghid) * 512;
        const float* W3 = Whh + (size_t)(1536 + ghid) * 512;
        const float b0 = bhh[ghid], b1 = bhh[512 + ghid];
        const float b2 = bhh[1024 + ghid], b3 = bhh[1536 + ghid];
        float c0 = 0.f, c1 = 0.f;
        for (int t = 0; t < 32; ++t) {
            const int rowA = r0 + r2, rowB = r0 + r2 + 8;
            const float* giA = gi + ((size_t)t * 128 + rowA) * 2048;
            const float* giB = gi + ((size_t)t * 128 + rowB) * 2048;
            float s00 = b0 + giA[ghid],        s01 = b1 + giA[512 + ghid];
            float s02 = b2 + giA[1024 + ghid], s03 = b3 + giA[1536 + ghid];
            float s10 = b0 + giB[ghid],        s11 = b1 + giB[512 + ghid];
            float s12 = b2 + giB[1024 + ghid], s13 = b3 + giB[1536 + ghid];
            if (t > 0) {
                const float* hsrc = hbuf + (size_t)(t & 1) * 65536;
                for (int idx = tid; idx < 8192; idx += 256) {
                    const int rr = idx >> 9, kk = idx & 511;
                    smem[rr * 520 + kk] = ldc(hsrc + (size_t)(r0 + rr) * 512 + kk);
                }
                __syncthreads();
                const float* ha = smem + r2 * 520;
                const float* hb = smem + (r2 + 8) * 520;
                for (int k = 0; k < 512; k += 4) {
                    const float4 a  = *(const float4*)(ha + k);
                    const float4 b  = *(const float4*)(hb + k);
                    const float4 wi = *(const float4*)(W0 + k);
                    const float4 wf = *(const float4*)(W1 + k);
                    const float4 wgv = *(const float4*)(W2 + k);
                    const float4 wo = *(const float4*)(W3 + k);
                    s00 += a.x*wi.x + a.y*wi.y + a.z*wi.z + a.w*wi.w;
                    s01 += a.x*wf.x + a.y*wf.y + a.z*wf.z + a.w*wf.w;
                    s02 += a.x*wgv.x + a.y*wgv.y + a.z*wgv.z + a.w*wgv.w;
                    s03 += a.x*wo.x + a.y*wo.y + a.z*wo.z + a.w*wo.w;
                    s10 += b.x*wi.x + b.y*wi.y + b.z*wi.z + b.w*wi.w;
                    s11 += b.x*wf.x + b.y*wf.y + b.z*wf.z + b.w*wf.w;
                    s12 += b.x*wgv.x + b.y*wgv.y + b.z*wgv.z + b.w*wgv.w;
                    s13 += b.x*wo.x + b.y*wo.y + b.z*wo.z + b.w*wo.w;
                }
            }
            c0 = sigf(s01) * c0 + sigf(s00) * tanhf(s02);
            const float hA = sigf(s03) * tanhf(c0);
            c1 = sigf(s11) * c1 + sigf(s10) * tanhf(s12);
            const float hB = sigf(s13) * tanhf(c1);
            float* hdst = hbuf + (size_t)((t + 1) & 1) * 65536;
            stc(hdst + (size_t)rowA * 512 + ghid, hA);
            stc(hdst + (size_t)rowB * 512 + ghid, hB);
            lstm_out[((size_t)t * 128 + rowA) * 512 + ghid] = hA;
            lstm_out[((size_t)t * 128 + rowB) * 512 + ghid] = hB;
            podbar(pbar, 16);
        }
        return;
    }

    // ============================= GNN pods =============================
    const int pod = wg >> 4, wip = wg & 15;
    int* pbar = bar + pod * 64;
    const int b_loc = wip >> 2, cb = wip & 3;
    const int bg = pod * 4 + b_loc;
    float* GGp = GG + (size_t)pod * 12288;
    float* hkp = hk + (size_t)pod * 512;

    for (int l = 0; l < 2; ++l) {
        const float* WtBl = WtB + (size_t)l * 1572864;
        const float* WrTl = WrT + (size_t)l * 524288;
        const float* cbhl = cbhh_all + l * 1536;
        const float* pbil = pbih_all + l * 1536;
        const float* aW   = attnW_all + l * 1024;
        const float  ab   = attnb_all[l];
        const float* Hin  = l ? H1 : H0;
        float* Hout = l ? H2 : H1;
        // zero parity-0 M / Mt
        {
            const int idx = wip * 256 + tid;
            if (idx < 2048) {
                stc(Mbuf + (size_t)pod * 2048 + idx, 0.f);
                stc(Mtbuf + (size_t)pod * 2048 + idx, 0.f);
            }
        }
        podbar(pbar, 16);
        for (int i = 0; i < 128; ++i) {
            const int par = i & 1;
            const float* Mtp = Mtbuf + ((size_t)par * 8 + pod) * 2048;
            const float* Mp  = Mbuf  + ((size_t)par * 8 + pod) * 2048;
            float* Mtn = Mtbuf + ((size_t)(1 - par) * 8 + pod) * 2048;
            float* Mn  = Mbuf  + ((size_t)(1 - par) * 8 + pod) * 2048;
            // ---------------- Phase B: GG = M @ [cWhh|pWih]^T + bias -----
            for (int idx = tid; idx < 2048; idx += 256) smem[idx] = ldc(Mtp + idx);
            __syncthreads();
            if (tid < 192) {
                const int col = wip * 192 + tid;
                const float* wp = WtBl + col;
                float a0 = 0.f, a1 = 0.f, a2 = 0.f, a3 = 0.f;
                for (int k = 0; k < 512; k += 4) {
                    const float w0 = wp[(size_t)(k + 0) * 3072];
                    const float w1 = wp[(size_t)(k + 1) * 3072];
                    const float w2 = wp[(size_t)(k + 2) * 3072];
                    const float w3 = wp[(size_t)(k + 3) * 3072];
                    const float4 m0 = *(const float4*)(smem + (k + 0) * 4);
                    const float4 m1 = *(const float4*)(smem + (k + 1) * 4);
                    const float4 m2 = *(const float4*)(smem + (k + 2) * 4);
                    const float4 m3 = *(const float4*)(smem + (k + 3) * 4);
                    a0 += w0*m0.x + w1*m1.x + w2*m2.x + w3*m3.x;
                    a1 += w0*m0.y + w1*m1.y + w2*m2.y + w3*m3.y;
                    a2 += w0*m0.z + w1*m1.z + w2*m2.z + w3*m3.z;
                    a3 += w0*m0.w + w1*m1.w + w2*m2.w + w3*m3.w;
                }
                const float bias = (col < 1536) ? cbhl[col] : pbil[col - 1536];
                stc(GGp + 0 * 3072 + col, a0 + bias);
                stc(GGp + 1 * 3072 + col, a1 + bias);
                stc(GGp + 2 * 3072 + col, a2 + bias);
                stc(GGp + 3 * 3072 + col, a3 + bias);
            }
            podbar(pbar, 16);
            // ---------------- Phase CA ----------------------------------
            {
                float* hs   = smem;
                float* v0s  = smem + 512;
                float* v1s  = smem + 640;
                float* wL0  = smem + 768;
                float* wL1  = smem + 896;
                float* part = smem + 1024;
                float* red  = smem + 1280;
                const float* pc = preQc + ((size_t)bg * 128 + i) * 1536;
                const float* pp = preQp + ((size_t)bg * 128 + i) * 1536;
                const float* ggb = GGp + (size_t)b_loc * 3072;
                const float* Mrow = Mp + (size_t)b_loc * 512;
                const float* q = Hin + ((size_t)bg * 128 + i) * 512;
                float hkpart = 0.f;
                #pragma unroll
                for (int rep = 0; rep < 2; ++rep) {
                    const int jj = tid + rep * 256;
                    const float g0 = ldc(ggb + jj);
                    const float g1 = ldc(ggb + 512 + jj);
                    const float g2 = ldc(ggb + 1024 + jj);
                    const float g3 = ldc(ggb + 1536 + jj);
                    const float g4 = ldc(ggb + 2048 + jj);
                    const float g5 = ldc(ggb + 2560 + jj);
                    const float mv = ldc(Mrow + jj);
                    const float qv = ldc(q + jj);
                    const float rc = sigf(ldc(pc + jj) + g0);
                    const float zc = sigf(ldc(pc + 512 + jj) + g1);
                    const float nc = tanhf(ldc(pc + 1024 + jj) + rc * g2);
                    const float oc = (1.f - zc) * nc + zc * mv;
                    const float rp = sigf(g3 + ldc(pp + jj));
                    const float zp = sigf(g4 + ldc(pp + 512 + jj));
                    const float np = tanhf(g5 + rp * ldc(pp + 1024 + jj));
                    const float op = (1.f - zp) * np + zp * qv;
                    const float h = oc + op;
                    hs[jj] = h;
                    if (cb == 0) stc(Hout + ((size_t)bg * 128 + i) * 512 + jj, h);
                    hkpart += h * aW[512 + jj];
                }
                const float hk_i = blk_sum(hkpart, red);
                if (cb == 0 && tid == 0) stc(hkp + b_loc * 128 + i, hk_i);
                __syncthreads();
                // V projection (coalesced via WrT)
                const int dloc = tid & 127, sel = tid >> 7;
                const int cc = cb * 128 + dloc;
                const int wcol = sel * 512 + cc;
                float vacc = 0.f;
                for (int k = 0; k < 512; k += 4) {
                    const float4 h4 = *(const float4*)(hs + k);
                    vacc += h4.x * WrTl[(size_t)(k + 0) * 1024 + wcol]
                          + h4.y * WrTl[(size_t)(k + 1) * 1024 + wcol]
                          + h4.z * WrTl[(size_t)(k + 2) * 1024 + wcol]
                          + h4.w * WrTl[(size_t)(k + 3) * 1024 + wcol];
                }
                (sel ? V1 : V0)[((size_t)bg * 128 + i) * 512 + cc] = vacc;  // same-WG reuse only
                if (sel) v1s[dloc] = vacc; else v0s[dloc] = vacc;
                // softmax(i+1) + M(i+1)
                if (i < 127) {
                    const int nx = i + 1;
                    const float* qn = Hin + ((size_t)bg * 128 + nx) * 512;
                    const float qp2 = ldc(qn + tid) * aW[tid]
                                    + ldc(qn + tid + 256) * aW[tid + 256];
                    const float qdot = blk_sum(qp2, red) + ab;
                    const float* ar = adj + ((size_t)bg * 128 + nx) * 128;
                    float alpha = -INFINITY;
                    if (tid <= i) {
                        const float hkn = (tid == i) ? hk_i : ldc(hkp + b_loc * 128 + tid);
                        alpha = qdot + hkn - (1.f - ar[tid]) * 1e30f;
                    }
                    const float mx = blk_max(alpha, red);
                    const float e = (tid <= i) ? __expf(alpha - mx) : 0.f;
                    const float esum = blk_sum(e, red);
                    if (tid <= i) {
                        const float w = e / esum;
                        const float s = smk[((size_t)bg * 128 + nx) * 128 + tid];
                        wL0[tid] = (s != 0.f) ? w : 0.f;
                        wL1[tid] = (s != 0.f) ? 0.f : w;
                    }
                    __syncthreads();
                    const int half = tid >> 7;
                    const float* Vb0 = V0 + ((size_t)bg * 128) * 512 + cb * 128 + dloc;
                    const float* Vb1 = V1 + ((size_t)bg * 128) * 512 + cb * 128 + dloc;
                    float acc = 0.f;
                    for (int n = half; n < i; n += 2)
                        acc += wL0[n] * Vb0[(size_t)n * 512] + wL1[n] * Vb1[(size_t)n * 512];
                    part[half * 128 + dloc] = acc;
                    __syncthreads();
                    if (tid < 128) {
                        const float m = part[tid] + part[128 + tid]
                                      + wL0[i] * v0s[tid] + wL1[i] * v1s[tid];
                        stc(Mn + (size_t)b_loc * 512 + cb * 128 + tid, m);
                        stc(Mtn + (size_t)(cb * 128 + tid) * 4 + b_loc, m);
                    }
                }
            }
            podbar(pbar, 16);
        }
        // -------- in-pod layer-1 preQ GEMM (after layer-0 scan) ---------
        // A is read DIRECTLY from H1 via ldc (sc1) — H1 was stc-written by
        // this pod and pod-barrier'd, so this is coherent. No staging copy.
        if (l == 0) {
            float* As = smem;
            float* Ws = smem + 1152;
            const int lr = tid >> 2, lk = (tid & 3) << 2;
            const int tm = (tid & 15) << 2, tn = (tid >> 4) << 2;
            const float* Hbase = H1 + (size_t)pod * 262144;
            for (int tile = wip; tile < 384; tile += 16) {
                const int rt = tile / 48, ctile = tile % 48;
                const int m0 = rt * 64, n0g = ctile * 64;
                const float* Wsrc; const float* bsrc; float* dst; int nloc;
                if (n0g < 1536) { Wsrc = cWih1; bsrc = cbih1; dst = preQc; nloc = n0g; }
                else            { Wsrc = pWhh1; bsrc = pbhh1; dst = preQp; nloc = n0g - 1536; }
                float acc[4][4] = {};
                for (int k0 = 0; k0 < 512; k0 += 16) {
                    __syncthreads();
                    const float* arow = Hbase + (size_t)(m0 + lr) * 512 + k0 + lk;
                    const float a0 = ldc(arow + 0);
                    const float a1 = ldc(arow + 1);
                    const float a2 = ldc(arow + 2);
                    const float a3 = ldc(arow + 3);
                    const float4 wv = *(const float4*)(Wsrc + (size_t)(nloc + lr) * 512 + k0 + lk);
                    As[(lk + 0) * 68 + lr] = a0; As[(lk + 1) * 68 + lr] = a1;
                    As[(lk + 2) * 68 + lr] = a2; As[(lk + 3) * 68 + lr] = a3;
                    Ws[(lk + 0) * 68 + lr] = wv.x; Ws[(lk + 1) * 68 + lr] = wv.y;
                    Ws[(lk + 2) * 68 + lr] = wv.z; Ws[(lk + 3) * 68 + lr] = wv.w;
                    __syncthreads();
                    #pragma unroll
                    for (int kk = 0; kk < 16; ++kk) {
                        float a[4], b[4];
                        #pragma unroll
                        for (int u = 0; u < 4; ++u) {
                            a[u] = As[kk * 68 + tm + u];
                            b[u] = Ws[kk * 68 + tn + u];
                        }
                        #pragma unroll
                        for (int ii = 0; ii < 4; ++ii)
                            #pragma unroll
                            for (int jj = 0; jj < 4; ++jj)
                                acc[ii][jj] += a[ii] * b[jj];
                    }
                }
                #pragma unroll
                for (int ii = 0; ii < 4; ++ii)
                    #pragma unroll
                    for (int jj = 0; jj < 4; ++jj)
                        stc(dst + (size_t)(pod * 512 + m0 + tm + ii) * 1536 + nloc + tn + jj,
                            acc[ii][jj] + bsrc[nloc + tn + jj]);
                __syncthreads();
            }
            podbar(pbar, 16);
        }
    }
}

// ---------------------------------------------------------------------------
__global__ __launch_bounds__(256) void out_gemm(
    const float* __restrict__ x2, const float* __restrict__ W,
    const float* __restrict__ bias, float* __restrict__ out)
{
    __shared__ float xs[16 * 516];
    const int tid = threadIdx.x;
    const int r0 = blockIdx.x * 16;
    for (int idx = tid; idx < 16 * 512; idx += 256) {
        const int rr = idx >> 9, kk = idx & 511;
        xs[rr * 516 + kk] = x2[(size_t)(r0 + rr) * 512 + kk];
    }
    __syncthreads();
    if (tid < 128) {
        const int r = tid >> 3, c = tid & 7;
        if (c < 7) {
            float acc = bias[c];
            const float* wr = W + c * 512;
            const float* xr = xs + r * 516;
            for (int k = 0; k < 512; ++k) acc += xr[k] * wr[k];
            out[(size_t)(r0 + r) * 7 + c] = acc;
        }
    }
}

// ---------------------------------------------------------------------------
extern "C" void kernel_launch(void* const* d_in, const int* in_sizes, int n_in,
                              void* d_out, int out_size, void* d_ws, size_t ws_size,
                              hipStream_t stream) {
    (void)in_sizes; (void)n_in; (void)out_size; (void)ws_size;
    const float* feat     = (const float*)d_in[0];
    const float* adj      = (const float*)d_in[1];
    const float* smask    = (const float*)d_in[2];
    const float* lstm_Wih = (const float*)d_in[5];
    const float* lstm_Whh = (const float*)d_in[6];
    const float* lstm_bih = (const float*)d_in[7];
    const float* lstm_bhh = (const float*)d_in[8];
    const float* fc1_W    = (const float*)d_in[9];
    const float* fc1_b    = (const float*)d_in[10];
    const float* attn_W   = (const float*)d_in[11];
    const float* attn_b   = (const float*)d_in[12];
    const float* Wr0      = (const float*)d_in[13];
    const float* Wr1      = (const float*)d_in[14];
    const float* gruC_Wih = (const float*)d_in[15];
    const float* gruC_Whh = (const float*)d_in[16];
    const float* gruC_bih = (const float*)d_in[17];
    const float* gruC_bhh = (const float*)d_in[18];
    const float* gruP_Wih = (const float*)d_in[19];
    const float* gruP_Whh = (const float*)d_in[20];
    const float* gruP_bih = (const float*)d_in[21];
    const float* gruP_bhh = (const float*)d_in[22];
    const float* mlp0_W   = (const float*)d_in[23];
    const float* mlp0_b   = (const float*)d_in[24];
    const float* mlp1_W   = (const float*)d_in[25];
    const float* mlp1_b   = (const float*)d_in[26];
    const float* out_W    = (const float*)d_in[27];
    const float* out_b    = (const float*)d_in[28];

    float* ws       = (float*)d_ws;
    float* lstm_gi  = ws;                       // 8,388,608
    float* lstm_out = lstm_gi + 8388608;        // 2,097,152
    float* H0       = lstm_out + 2097152;
    float* H1       = H0 + 2097152;
    float* H2       = H1 + 2097152;
    float* preQc    = H2 + 2097152;             // 6,291,456
    float* preQp    = preQc + 6291456;
    float* V0       = preQp + 6291456;          // 2,097,152 (reused as x1)
    float* V1       = V0 + 2097152;             // (reused as x2)
    float* hkbuf    = V1 + 2097152;             // 4,096
    float* Mbuf     = hkbuf + 4096;             // 32,768 [par][pod][4][512]
    float* Mtbuf    = Mbuf + 32768;             // 32,768 [par][pod][512][4]
    float* GG       = Mtbuf + 32768;            // 98,304
    float* hbuf     = GG + 98304;               // 131,072
    float* WtB      = hbuf + 131072;            // 3,145,728 [2][512][3072]
    float* WrT      = WtB + 3145728;            // 1,048,576 [2][512][1024]
    int*   bar      = (int*)(WrT + 1048576);    // 1,024 ints

    const dim3 blk(256);
    init_bar<<<1, 1024, 0, stream>>>(bar);

    // weight transposes for coalesced scan-phase loads
    for (int l = 0; l < 2; ++l) {
        tpose_cat<<<dim3(48, 8), blk, 0, stream>>>(
            gruC_Whh + (size_t)l * 1536 * 512, gruP_Wih + (size_t)l * 1536 * 512,
            WtB + (size_t)l * 1572864, 1536, 3072);
        tpose_cat<<<dim3(16, 8), blk, 0, stream>>>(
            Wr0 + (size_t)l * 512 * 512, Wr1 + (size_t)l * 512 * 512,
            WrT + (size_t)l * 524288, 512, 1024);
    }

    // parallel-phase GEMMs
    gemm_nt<<<dim3(64, 8), blk, 0, stream>>>(feat, fc1_W, fc1_b, H0, 4096, 512, 1024, 1);
    gemm_nt<<<dim3(64, 32), blk, 0, stream>>>(feat, lstm_Wih, lstm_bih, lstm_gi, 4096, 2048, 1024, 0);
    gemm_nt<<<dim3(64, 24), blk, 0, stream>>>(H0, gruC_Wih, gruC_bih, preQc, 4096, 1536, 512, 0);
    gemm_nt<<<dim3(64, 24), blk, 0, stream>>>(H0, gruP_Whh, gruP_bhh, preQp, 4096, 1536, 512, 0);

    // persistent fused LSTM + 2-layer GNN scan
    fused_pers<<<256, blk, 0, stream>>>(
        H0, H1, H2, adj, smask, preQc, preQp, WtB, WrT,
        gruC_bhh, gruP_bih, attn_W, attn_b,
        gruC_Wih + (size_t)1536 * 512, gruC_bih + 1536,
        gruP_Whh + (size_t)1536 * 512, gruP_bhh + 1536,
        V0, V1, hkbuf, Mbuf, Mtbuf, GG,
        lstm_gi, lstm_Whh, lstm_bhh, hbuf, lstm_out, bar);

    // head
    float* x1 = V0;
    float* x2 = V1;
    gemm_cat<<<dim3(64, 8), blk, 0, stream>>>(H0, H1, H2, feat, lstm_out, mlp0_W, mlp0_b, x1);
    gemm_nt<<<dim3(64, 8), blk, 0, stream>>>(x1, mlp1_W, mlp1_b, x2, 4096, 512, 512, 1);
    out_gemm<<<256, blk, 0, stream>>>(x2, out_W, out_b, (float*)d_out);
}